// Round 5
// baseline (580.752 us; speedup 1.0000x reference)
//
#include <hip/hip_runtime.h>
#include <hip/hip_bf16.h>

// PhysicsGraphFusion: B=1024, N=7, D=1024
// Outputs (flat): fused (B*D), updated (B*N*D), imp (B*N), attn (B*N*N), phys (1), align (1)

typedef __attribute__((ext_vector_type(8))) short bf16x8;
typedef __attribute__((ext_vector_type(4))) float f32x4;
typedef __attribute__((ext_vector_type(16))) float f32x16;

__constant__ float c_adj[49] = {
    1,1,0,0,1,1,1,
    1,1,1,1,1,1,1,
    0,1,1,0,1,0,1,
    0,1,0,1,1,1,1,
    1,1,1,1,1,1,1,
    1,1,0,1,1,1,1,
    1,1,1,1,1,1,1};

// gelu via Abramowitz-Stegun 7.1.26 erf (|err| < 1.5e-7, ~12 VALU ops).
__device__ __forceinline__ float gelu_f(float x) {
    float z = fabsf(x) * 0.70710678118654752f;
    float t = 1.0f / (1.0f + 0.3275911f * z);
    float poly = ((((1.061405429f * t - 1.453152027f) * t + 1.421413741f) * t
                  - 0.284496736f) * t + 0.254829592f) * t;
    float e = __expf(-z * z);
    float erf_abs = 1.0f - poly * e;
    float erf = copysignf(erf_abs, x);
    return 0.5f * x * (1.0f + erf);
}
__device__ __forceinline__ float b2f(unsigned short u) {
    unsigned int x = ((unsigned int)u) << 16;
    union { unsigned int i; float f; } c; c.i = x; return c.f;
}
__device__ __forceinline__ unsigned short f2b(float f) {
    __hip_bfloat16 h = __float2bfloat16(f);
    union { __hip_bfloat16 b; unsigned short u; } c; c.b = h; return c.u;
}

__device__ __forceinline__ void gload_lds16(const void* g, void* l) {
    __builtin_amdgcn_global_load_lds(
        (const __attribute__((address_space(1))) unsigned int*)g,
        (__attribute__((address_space(3))) unsigned int*)l, 16, 0, 0);
}

// row mapping: 0: r->r ; 1: r->r*7+6 (ctx rows) ; 2: r->r-r%7+6 (ctx broadcast)
__device__ __forceinline__ int maprow(int r, int mode) {
    if (mode == 1) return r * 7 + 6;
    if (mode == 2) return r - r % 7 + 6;
    return r;
}

// ---------------------------------------------------------------------------
// 128x128-tile, 4-wave (256-thread) bf16 MFMA GEMM using 32x32x16 MFMA,
// 3-slot LDS ring, counted vmcnt.
//
// WHY 32x32 frags: R1-R4 showed all 16x16-frag schedules converge at
// MfmaUtil ~25% because the LDS pipe is the bound: 64KB LDS traffic per
// block-K-tile for 1.05 MFLOP (16 FLOP/byte) = ~104us of pure LDS time for
// the QKV GEMM. Wave tile 64x64 via 2x2 of 32x32x16 frags does 8 MFMA per
// 8 b128 reads -> 48KB per block-K-tile (22 FLOP/byte, 1.45x less).
// MFMA 32x32x16: A/B = 8 bf16 (4 VGPR), layout row=lane&31, k=(lane>>5)*8+i
// (32-lane analog of the verified 16x16 mapping); C/D = 16 f32,
// col=lane&31, row=(reg&3)+8*(reg>>2)+4*(lane>>5)  [m74/m101-verified].
//
// Ring: 3 slots x (128x32) per operand = 48 KB LDS. Iter kt: issue
// stage(kt+2) (4 loads/thread) -> ds_read frags(kt) -> 8 MFMA
// (compiler-managed lgkmcnt) -> vmcnt(4) [tail vmcnt(0)] -> s_barrier.
// Race proof: iter kt reads slot kt%3, writes slot (kt+2)%3 (distinct
// mod 3); slot written at kt was last read at iter kt-1, which all waves
// left at the barrier ending iter kt-1 (reads consumed by MFMA waits
// before the barrier). Counted vmcnt(4) leaves tile kt+2's 4 per-thread
// loads in flight across the barrier.
// Chunk swizzle: LDS chunk = glb chunk ^ ((row>>1)&3). For the 32-lane
// frag read (rows 0..31, fixed logical chunk) the swizzled chunks cycle
// every 8 rows -> all 8 bank-quads covered, 2 lanes/bank = free.
// XCD swizzle: bijective (grids 2240, 448 both % 8 == 0).
// ---------------------------------------------------------------------------
__global__ __launch_bounds__(256) void gemm128w32(
    const unsigned short* __restrict__ A1, int a1Mode,
    const unsigned short* __restrict__ A2, int a2Mode,
    const unsigned short* __restrict__ WT, int ldw,
    const float* __restrict__ bias,
    const float* __restrict__ resid,
    float* __restrict__ Cf,
    unsigned short* __restrict__ Cb, size_t segStride,
    int K, int act)
{
    __shared__ short As[3][128 * 32];
    __shared__ short Bs[3][128 * 32];
    const int tid = threadIdx.x;
    const int lane = tid & 63;
    const int w = tid >> 6;            // 4 waves (2x2)
    const int wr = (w >> 1) * 64;
    const int wc = (w & 1) * 64;

    // bijective XCD swizzle
    int lin = blockIdx.y * gridDim.x + blockIdx.x;
    const int nwg = gridDim.x * gridDim.y;
    const int cpx = nwg >> 3;
    lin = (lin & 7) * cpx + (lin >> 3);
    const int row0 = (lin / gridDim.x) * 128;
    const int col0 = (lin % gridDim.x) * 128;

    const int l31 = lane & 31;
    const int hi  = lane >> 5;
    const int xorv = (l31 >> 1) & 3;
    // per-lane LDS offsets (shorts)
    int aRow[2], bRow[2], cOff[2];
    aRow[0] = (wr + l31) * 32;       aRow[1] = (wr + 32 + l31) * 32;
    bRow[0] = (wc + l31) * 32;       bRow[1] = (wc + 32 + l31) * 32;
    cOff[0] = ((hi)     ^ xorv) * 8;
    cOff[1] = ((2 + hi) ^ xorv) * 8;

    const int NTt = K >> 5;

    auto stage = [&](int ktn) {
        int k0n = ktn * 32;
        const unsigned short* srcA; int mode; int kbase;
        if (k0n < 1024) { srcA = A1; mode = a1Mode; kbase = k0n; }
        else            { srcA = A2; mode = a2Mode; kbase = k0n - 1024; }
        int slot = ktn % 3;
        #pragma unroll
        for (int rnd = 0; rnd < 2; ++rnd) {
            int c2 = rnd * 256 + tid;
            int m = c2 >> 2, ch = c2 & 3;
            int kc = (ch ^ ((m >> 1) & 3)) * 8;   // pre-swizzled global chunk
            int rr = maprow(row0 + m, mode);
            gload_lds16(srcA + (size_t)rr * 1024 + kbase + kc, &As[slot][c2 * 8]);
        }
        #pragma unroll
        for (int rnd = 0; rnd < 2; ++rnd) {
            int c2 = rnd * 256 + tid;
            int n = c2 >> 2, ch = c2 & 3;
            int kc = (ch ^ ((n >> 1) & 3)) * 8;
            gload_lds16(WT + (size_t)(col0 + n) * ldw + k0n + kc, &Bs[slot][c2 * 8]);
        }
    };

    f32x16 acc[2][2] = {};

    // prologue: stage tiles 0,1; wait tile 0 (vmcnt(4): tile 1 in flight)
    stage(0);
    if (NTt > 1) stage(1);
    asm volatile("s_waitcnt vmcnt(4)" ::: "memory");
    asm volatile("s_barrier" ::: "memory");

    for (int kt = 0; kt < NTt; ++kt) {
        const short* Ab = &As[kt % 3][0];
        const short* Bb = &Bs[kt % 3][0];

        if (kt + 2 < NTt) stage(kt + 2);   // 2-tile lookahead

        bf16x8 af[2][2], bfv[2][2];
        #pragma unroll
        for (int ks = 0; ks < 2; ++ks) {
            #pragma unroll
            for (int mf = 0; mf < 2; ++mf)
                af[mf][ks] = *(const bf16x8*)(Ab + aRow[mf] + cOff[ks]);
            #pragma unroll
            for (int nf = 0; nf < 2; ++nf)
                bfv[nf][ks] = *(const bf16x8*)(Bb + bRow[nf] + cOff[ks]);
        }

        __builtin_amdgcn_s_setprio(1);
        #pragma unroll
        for (int ks = 0; ks < 2; ++ks)
            #pragma unroll
            for (int mf = 0; mf < 2; ++mf)
                #pragma unroll
                for (int nf = 0; nf < 2; ++nf)
                    acc[mf][nf] = __builtin_amdgcn_mfma_f32_32x32x16_bf16(
                        af[mf][ks], bfv[nf][ks], acc[mf][nf], 0, 0, 0);
        __builtin_amdgcn_s_setprio(0);

        if (kt < NTt - 2) asm volatile("s_waitcnt vmcnt(4)" ::: "memory");
        else              asm volatile("s_waitcnt vmcnt(0)" ::: "memory");
        asm volatile("s_barrier" ::: "memory");
    }

    // epilogue: C/D layout col=lane&31, row=(reg&3)+8*(reg>>2)+4*hi
    #pragma unroll
    for (int mf = 0; mf < 2; ++mf) {
        #pragma unroll
        for (int nf = 0; nf < 2; ++nf) {
            int c = col0 + wc + nf * 32 + l31;
            float bv = bias ? bias[c] : 0.0f;
            int seg = c >> 10, c0 = c & 1023;
            #pragma unroll
            for (int r = 0; r < 16; ++r) {
                int row = row0 + wr + mf * 32 + (r & 3) + 8 * (r >> 2) + 4 * hi;
                float vv = acc[mf][nf][r] + bv;
                if (act) vv = gelu_f(vv);
                if (resid) vv += resid[(size_t)row * 1024 + c];
                if (Cf) Cf[(size_t)row * 1024 + c] = vv;
                if (Cb) Cb[(size_t)seg * segStride + (size_t)row * 1024 + c0] = f2b(vv);
            }
        }
    }
}

// ---------------------------------------------------------------------------
// 64x128-tile bf16 MFMA GEMM (only used for the small ctx GEMM).
// ---------------------------------------------------------------------------
__global__ __launch_bounds__(256) void gemm64x128(
    const unsigned short* __restrict__ A1, int a1Mode,
    const unsigned short* __restrict__ A2, int a2Mode,
    const unsigned short* __restrict__ WT, int ldw,
    const float* __restrict__ bias,
    const float* __restrict__ resid,
    float* __restrict__ Cf,
    unsigned short* __restrict__ Cb,
    int K, int act)
{
    __shared__ short As[64 * 32];
    __shared__ short Bs[128 * 32];
    const int tid = threadIdx.x;
    const int lane = tid & 63;
    const int w = tid >> 6;
    const int wc = w * 32;
    const int row0 = blockIdx.y * 64;
    const int col0 = blockIdx.x * 128;
    const int fr = lane & 15;
    const int fko = (((lane >> 4) ^ ((fr >> 1) & 3)) << 3);

    f32x4 acc[4][2] = {};

    for (int k0 = 0; k0 < K; k0 += 32) {
        const unsigned short* srcA; int mode; int kbase;
        if (k0 < 1024) { srcA = A1; mode = a1Mode; kbase = k0; }
        else           { srcA = A2; mode = a2Mode; kbase = k0 - 1024; }
        {
            int m = tid >> 2, ch = tid & 3;
            int kc = (ch ^ ((m >> 1) & 3)) * 8;
            int rr = maprow(row0 + m, mode);
            gload_lds16(srcA + (size_t)rr * 1024 + kbase + kc, &As[tid * 8]);
        }
        #pragma unroll
        for (int rnd = 0; rnd < 2; ++rnd) {
            int c = rnd * 256 + tid;
            int n = c >> 2, ch = c & 3;
            int kc = (ch ^ ((n >> 1) & 3)) * 8;
            gload_lds16(WT + (size_t)(col0 + n) * ldw + k0 + kc, &Bs[c * 8]);
        }
        __syncthreads();
        bf16x8 af[4], bf_[2];
        #pragma unroll
        for (int i = 0; i < 4; ++i)
            af[i] = *(const bf16x8*)(&As[(i * 16 + fr) * 32 + fko]);
        #pragma unroll
        for (int j = 0; j < 2; ++j)
            bf_[j] = *(const bf16x8*)(&Bs[(wc + j * 16 + fr) * 32 + fko]);
        #pragma unroll
        for (int i = 0; i < 4; ++i)
            #pragma unroll
            for (int j = 0; j < 2; ++j)
                acc[i][j] = __builtin_amdgcn_mfma_f32_16x16x32_bf16(
                    af[i], bf_[j], acc[i][j], 0, 0, 0);
        __syncthreads();
    }

    const int qrow = (lane >> 4) * 4;
    const int qcol = lane & 15;
    #pragma unroll
    for (int i = 0; i < 4; ++i) {
        int rbase = row0 + i * 16 + qrow;
        #pragma unroll
        for (int j = 0; j < 2; ++j) {
            int c = col0 + wc + j * 16 + qcol;
            float bv = bias ? bias[c] : 0.0f;
            #pragma unroll
            for (int reg = 0; reg < 4; ++reg) {
                int r = rbase + reg;
                float vv = acc[i][j][reg] + bv;
                if (act) vv = gelu_f(vv);
                if (resid) vv += resid[(size_t)r * 1024 + c];
                if (Cf) Cf[(size_t)r * 1024 + c] = vv;
                if (Cb) Cb[(size_t)r * 1024 + c] = f2b(vv);
            }
        }
    }
}

// fp32 -> bf16 elementwise cast
__global__ __launch_bounds__(256) void cast_f2b(
    const float* __restrict__ in, unsigned short* __restrict__ out, int n)
{
    int i = (blockIdx.x * 256 + threadIdx.x) * 4;
    if (i >= n) return;
    float4 v = *(const float4*)(in + i);
    ushort4 o;
    o.x = f2b(v.x); o.y = f2b(v.y); o.z = f2b(v.z); o.w = f2b(v.w);
    *(ushort4*)(out + i) = o;
}

// All weight transposes+casts in one dispatch. grid (32, 64, 9).
__global__ __launch_bounds__(256) void tcast_all(
    const float* __restrict__ Wq, const float* __restrict__ Wk,
    const float* __restrict__ Wv, const float* __restrict__ We1,
    const float* __restrict__ Wu1, const float* __restrict__ Wu2,
    const float* __restrict__ Wi1,
    unsigned short* __restrict__ WT_all, unsigned short* __restrict__ Wu1T,
    unsigned short* __restrict__ Wu2T, unsigned short* __restrict__ Wi1T)
{
    const int z = blockIdx.z;
    const float* src; unsigned short* dst; int R;
    switch (z) {
        case 0: src = Wq;            dst = WT_all;               R = 1024; break;
        case 1: src = Wk;            dst = WT_all + 1024 * 1024; R = 1024; break;
        case 2: src = Wv;            dst = WT_all + 2048 * 1024; R = 1024; break;
        case 3: src = We1;           dst = WT_all + 3072 * 1024; R = 1024; break;
        case 4: src = We1 + 1048576; dst = WT_all + 4096 * 1024; R = 1024; break;
        case 5: src = We1 + 2097152; dst = WT_all + 5120 * 1024; R = 1024; break;
        case 6: src = Wu1;           dst = Wu1T;                 R = 2048; break;
        case 7: src = Wu2;           dst = Wu2T;                 R = 1024; break;
        default: src = Wi1;          dst = Wi1T;                 R = 2048; break;
    }
    const int rt = blockIdx.y * 32;
    if (rt >= R) return;
    const int ct = blockIdx.x * 32;
    __shared__ float t[32][33];
    const int tx = threadIdx.x & 31, ty = threadIdx.x >> 5;
    #pragma unroll
    for (int s = 0; s < 4; ++s)
        t[ty + s * 8][tx] = src[(size_t)(rt + ty + s * 8) * 1024 + ct + tx];
    __syncthreads();
    #pragma unroll
    for (int s = 0; s < 4; ++s)
        dst[(size_t)(ct + ty + s * 8) * R + rt + tx] = f2b(t[tx][ty + s * 8]);
}

// bias_all[5120] = [bq | bk | bv | 0 | 0]; also zeroes the accum scratch
__global__ void build_bias(const float* __restrict__ bq,
                           const float* __restrict__ bk,
                           const float* __restrict__ bv,
                           float* __restrict__ bias_all,
                           float* __restrict__ acc)
{
    int i = blockIdx.x * 256 + threadIdx.x;
    if (i < 4) acc[i] = 0.f;
    if (i >= 5120) return;
    int seg = i >> 10, c = i & 1023;
    float v = 0.f;
    if (seg == 0) v = bq[c];
    else if (seg == 1) v = bk[c];
    else if (seg == 2) v = bv[c];
    bias_all[i] = v;
}

// ---------------------------------------------------------------------------
// One block per (b,n): edge MLP + logits + softmax + messages (bf16 in/out).
// All 7 m-partials in registers -> one reduction phase (2 barriers).
// msg may alias la (each block reads only its own la row, into regs first).
// ---------------------------------------------------------------------------
__global__ __launch_bounds__(256) void attn_msg_b(
    const unsigned short* __restrict__ q, const unsigned short* __restrict__ k,
    const unsigned short* __restrict__ v,
    const unsigned short* __restrict__ la, const unsigned short* __restrict__ rb,
    const float* __restrict__ cc,
    const float* __restrict__ We2, const float* __restrict__ be2,
    float* __restrict__ attn_out, unsigned short* __restrict__ msg)
{
    const int bn = blockIdx.x;
    const int b = bn / 7, n = bn % 7;
    const int tid = threadIdx.x;
    const int lane = tid & 63, wv = tid >> 6;
    const int d0 = tid * 4;
    __shared__ float red[4][14];
    __shared__ float sm[7];

    float qv[4], lav[4], wev[4];
    {
        ushort4 q4 = *(const ushort4*)(q + (size_t)bn * 1024 + d0);
        ushort4 l4 = *(const ushort4*)(la + (size_t)bn * 1024 + d0);
        float4 c4 = *(const float4*)(cc + (size_t)b * 1024 + d0);
        float4 w4 = *(const float4*)(We2 + d0);
        qv[0] = b2f(q4.x); qv[1] = b2f(q4.y); qv[2] = b2f(q4.z); qv[3] = b2f(q4.w);
        lav[0] = b2f(l4.x) + c4.x; lav[1] = b2f(l4.y) + c4.y;
        lav[2] = b2f(l4.z) + c4.z; lav[3] = b2f(l4.w) + c4.w;
        wev[0] = w4.x; wev[1] = w4.y; wev[2] = w4.z; wev[3] = w4.w;
    }

    float s1a[7], s2a[7];
    #pragma unroll
    for (int m = 0; m < 7; ++m) {
        ushort4 k4 = *(const ushort4*)(k  + (size_t)(b * 7 + m) * 1024 + d0);
        ushort4 r4 = *(const ushort4*)(rb + (size_t)(b * 7 + m) * 1024 + d0);
        s1a[m] = qv[0] * b2f(k4.x) + qv[1] * b2f(k4.y)
               + qv[2] * b2f(k4.z) + qv[3] * b2f(k4.w);
        s2a[m] = gelu_f(lav[0] + b2f(r4.x)) * wev[0]
               + gelu_f(lav[1] + b2f(r4.y)) * wev[1]
               + gelu_f(lav[2] + b2f(r4.z)) * wev[2]
               + gelu_f(lav[3] + b2f(r4.w)) * wev[3];
    }
    #pragma unroll
    for (int m = 0; m < 7; ++m) {
        float x1 = s1a[m], x2 = s2a[m];
        #pragma unroll
        for (int off = 32; off > 0; off >>= 1) {
            x1 += __shfl_down(x1, off);
            x2 += __shfl_down(x2, off);
        }
        if (lane == 0) { red[wv][m] = x1; red[wv][7 + m] = x2; }
    }
    __syncthreads();
    if (tid == 0) {
        float l[7];
        #pragma unroll
        for (int m = 0; m < 7; ++m) {
            float d1 = red[0][m] + red[1][m] + red[2][m] + red[3][m];
            float d2 = red[0][7 + m] + red[1][7 + m] + red[2][7 + m] + red[3][7 + m];
            l[m] = d1 * (1.0f / 32.0f) + d2 + be2[0]
                 + (c_adj[n * 7 + m] - 1.0f) * 10000.0f;
        }
        float mx = l[0];
        #pragma unroll
        for (int m = 1; m < 7; ++m) mx = fmaxf(mx, l[m]);
        float e[7], s = 0.f;
        #pragma unroll
        for (int m = 0; m < 7; ++m) { e[m] = __expf(l[m] - mx); s += e[m]; }
        float inv = 1.0f / s;
        #pragma unroll
        for (int m = 0; m < 7; ++m) {
            float wgt = e[m] * inv;
            sm[m] = wgt;
            attn_out[(size_t)bn * 7 + m] = wgt;
        }
    }
    __syncthreads();
    float wr_[7];
    #pragma unroll
    for (int m = 0; m < 7; ++m) wr_[m] = sm[m];
    float s0 = 0.f, s1 = 0.f, s2 = 0.f, s3 = 0.f;
    #pragma unroll
    for (int m = 0; m < 7; ++m) {
        ushort4 v4 = *(const ushort4*)(v + (size_t)(b * 7 + m) * 1024 + d0);
        s0 += wr_[m] * b2f(v4.x); s1 += wr_[m] * b2f(v4.y);
        s2 += wr_[m] * b2f(v4.z); s3 += wr_[m] * b2f(v4.w);
    }
    ushort4 o;
    o.x = f2b(s0); o.y = f2b(s1); o.z = f2b(s2); o.w = f2b(s3);
    *(ushort4*)(msg + (size_t)bn * 1024 + d0) = o;
}

// imp_logits[r] = dot(H[r,:], w2) + b2[0]   (H bf16)
__global__ __launch_bounds__(256) void row_dot_b(
    const unsigned short* __restrict__ H, const float* __restrict__ w2,
    const float* __restrict__ b2, float* __restrict__ out)
{
    const int r = blockIdx.x;
    const int tid = threadIdx.x;
    const int lane = tid & 63, wv = tid >> 6;
    __shared__ float red[4];
    const int d0 = tid * 4;
    ushort4 h4 = *(const ushort4*)(H + (size_t)r * 1024 + d0);
    float4 w4 = *(const float4*)(w2 + d0);
    float s = b2f(h4.x) * w4.x + b2f(h4.y) * w4.y
            + b2f(h4.z) * w4.z + b2f(h4.w) * w4.w;
    #pragma unroll
    for (int off = 32; off > 0; off >>= 1) s += __shfl_down(s, off);
    if (lane == 0) red[wv] = s;
    __syncthreads();
    if (tid == 0) out[r] = red[0] + red[1] + red[2] + red[3] + b2[0];
}

// per-b: softmax over N, cap/redistribute, imp; fused = sum_n imp*updated
__global__ __launch_bounds__(256) void imp_fused_k(
    const float* __restrict__ logits, const float* __restrict__ upd,
    float* __restrict__ imp_out, float* __restrict__ fused_out)
{
    const int b = blockIdx.x;
    const int tid = threadIdx.x;
    __shared__ float w[7];
    if (tid == 0) {
        float l[7], e[7];
        float mx = -1e30f;
        for (int i = 0; i < 7; ++i) { l[i] = logits[b * 7 + i]; mx = fmaxf(mx, l[i]); }
        float s = 0.f;
        for (int i = 0; i < 7; ++i) { e[i] = expf(l[i] - mx); s += e[i]; }
        float inv = 1.0f / s;
        float imp[7];
        for (int i = 0; i < 7; ++i) imp[i] = e[i] * inv;
        const float cap[7] = {1.f, 1.f, 1.f, 0.26f, 1.f, 1.f, 0.24f};
        const float fr[7]  = {1.f, 1.f, 1.f, 0.f,   1.f, 1.f, 0.f};
        float capped[7], capsum = 0.f, fmass = 0.f;
        for (int i = 0; i < 7; ++i) {
            capped[i] = fminf(imp[i], cap[i]);
            capsum += capped[i];
            fmass += imp[i] * fr[i];
        }
        float residual = fmaxf(1.0f - capsum, 0.0f);
        float redis[7], rs = 0.f;
        for (int i = 0; i < 7; ++i) {
            float fs = (fmass > 1e-6f) ? imp[i] * fr[i] / fmaxf(fmass, 1e-6f)
                                       : fr[i] * 0.2f;
            redis[i] = capped[i] + fs * residual;
            rs += redis[i];
        }
        float invr = 1.0f / fmaxf(rs, 1e-6f);
        for (int i = 0; i < 7; ++i) {
            float wi = redis[i] * invr;
            w[i] = wi;
            imp_out[b * 7 + i] = wi;
        }
    }
    __syncthreads();
    float wr[7];
    #pragma unroll
    for (int i = 0; i < 7; ++i) wr[i] = w[i];
    #pragma unroll
    for (int j = 0; j < 4; ++j) {
        int d = tid + j * 256;
        float s = 0.f;
        #pragma unroll
        for (int nn2 = 0; nn2 < 7; ++nn2)
            s += wr[nn2] * upd[(size_t)(b * 7 + nn2) * 1024 + d];
        fused_out[(size_t)b * 1024 + d] = s;
    }
}

__global__ __launch_bounds__(256) void physics_k(
    const float* __restrict__ upd, const float* __restrict__ fused,
    float* __restrict__ accums)
{
    const int b = blockIdx.x;
    const int tid = threadIdx.x;
    const int lane = tid & 63, wv = tid >> 6;
    __shared__ float u[7][1024];
    __shared__ float f[1024];
    __shared__ float wred[4][36];
    for (int idx = tid; idx < 7 * 1024; idx += 256)
        u[idx >> 10][idx & 1023] = upd[(size_t)b * 7168 + idx];
    for (int d = tid; d < 1024; d += 256)
        f[d] = fused[(size_t)b * 1024 + d];
    __syncthreads();

    float vals[36];
    #pragma unroll
    for (int i = 0; i < 36; ++i) vals[i] = 0.f;
    for (int d = tid; d < 1024; d += 256) {
        float x[7];
        #pragma unroll
        for (int n = 0; n < 7; ++n) x[n] = u[n][d];
        float fv = f[d];
        int idx = 0;
        #pragma unroll
        for (int n = 0; n < 7; ++n) {
            #pragma unroll
            for (int m = n; m < 7; ++m) vals[idx++] += x[n] * x[m];
        }
        #pragma unroll
        for (int n = 0; n < 7; ++n) vals[28 + n] += x[n] * fv;
        vals[35] += fv * fv;
    }
    #pragma unroll
    for (int i = 0; i < 36; ++i) {
        float s = vals[i];
        #pragma unroll
        for (int off = 32; off > 0; off >>= 1) s += __shfl_down(s, off);
        if (lane == 0) wred[wv][i] = s;
    }
    __syncthreads();
    if (tid == 0) {
        float tv[36];
        for (int i = 0; i < 36; ++i)
            tv[i] = wred[0][i] + wred[1][i] + wred[2][i] + wred[3][i];
        auto didx = [](int n, int m) -> int {
            if (n > m) { int t = n; n = m; m = t; }
            return n * 7 - n * (n - 1) / 2 + (m - n);
        };
        float norms[7];
        for (int n = 0; n < 7; ++n) norms[n] = sqrtf(tv[didx(n, n)]);
        float e = 0.f, nl = 0.f;
        for (int n = 0; n < 7; ++n)
            for (int m = 0; m < 7; ++m) {
                float cos_ = tv[didx(n, m)] / fmaxf(norms[n] * norms[m], 1e-8f);
                float adj = c_adj[n * 7 + m];
                e += (1.0f - cos_) * adj;
                if (adj == 0.0f && n != m) nl += fmaxf(cos_ - 0.35f, 0.0f);
            }
        float fnorm = sqrtf(tv[35]);
        float al = 0.f;
        for (int n = 0; n < 7; ++n) {
            float cosn = tv[28 + n] /
                         (fmaxf(norms[n], 1e-12f) * fmaxf(fnorm, 1e-12f));
            al += 1.0f - cosn;
        }
        atomicAdd(&accums[0], e);
        atomicAdd(&accums[1], nl);
        atomicAdd(&accums[2], al);
    }
}

__global__ void finalize_k(const float* __restrict__ a,
                           float* __restrict__ phys_o,
                           float* __restrict__ align_o)
{
    phys_o[0]  = a[0] / 41.0f + 0.5f * (a[1] / 8.0f);
    align_o[0] = a[2] * (1.0f / 7168.0f);
}

extern "C" void kernel_launch(void* const* d_in, const int* in_sizes, int n_in,
                              void* d_out, int out_size, void* d_ws, size_t ws_size,
                              hipStream_t stream)
{
    const float* nodes = (const float*)d_in[0];
    const float* Wq  = (const float*)d_in[1];
    const float* bq  = (const float*)d_in[2];
    const float* Wk  = (const float*)d_in[3];
    const float* bk  = (const float*)d_in[4];
    const float* Wv  = (const float*)d_in[5];
    const float* bv  = (const float*)d_in[6];
    const float* We1 = (const float*)d_in[7];
    const float* be1 = (const float*)d_in[8];
    const float* We2 = (const float*)d_in[9];
    const float* be2 = (const float*)d_in[10];
    const float* Wu1 = (const float*)d_in[11];
    const float* bu1 = (const float*)d_in[12];
    const float* Wu2 = (const float*)d_in[13];
    const float* bu2 = (const float*)d_in[14];
    const float* Wi1 = (const float*)d_in[15];
    const float* bi1 = (const float*)d_in[16];
    const float* Wi2 = (const float*)d_in[17];
    const float* bi2 = (const float*)d_in[18];

    float* out = (float*)d_out;
    float* fused_o = out;                            // 1,048,576
    float* upd_o   = out + 1048576;                  // 7,340,032
    float* imp_o   = out + 1048576 + 7340032;        // 7,168
    float* attn_o  = imp_o + 7168;                   // 50,176
    float* phys_o  = attn_o + 50176;                 // 1
    float* align_o = phys_o + 1;                     // 1

    const size_t BIG = 7340032;   // B*N*D
    const size_t MEG = 1048576;   // D*D
    char* p = (char*)d_ws;
    unsigned short* nodes_b = (unsigned short*)p; p += BIG * 2;
    unsigned short* qb      = (unsigned short*)p; p += BIG * 2;   // seg 0; reused: h_u
    unsigned short* kb      = (unsigned short*)p; p += BIG * 2;   // seg 1; reused: upd_b
    unsigned short* vb      = (unsigned short*)p; p += BIG * 2;   // seg 2; reused: h_i
    unsigned short* lab     = (unsigned short*)p; p += BIG * 2;   // seg 3; reused: msg
    unsigned short* rbb     = (unsigned short*)p; p += BIG * 2;   // seg 4
    unsigned short* WT_all  = (unsigned short*)p; p += (size_t)6144 * 1024 * 2;
    unsigned short* Wu1T    = (unsigned short*)p; p += 2 * MEG * 2;
    unsigned short* Wu2T    = (unsigned short*)p; p += MEG * 2;
    unsigned short* Wi1T    = (unsigned short*)p; p += 2 * MEG * 2;
    float* bias_all = (float*)p; p += 5120 * 4;
    float* ccf = (float*)p; p += MEG * 4;
    float* il  = (float*)p; p += 7168 * 4;
    float* acc = (float*)p; p += 4 * 4;
    unsigned short* msgb = lab;   // alias: safe (see attn_msg_b)
    unsigned short* hub  = qb;
    unsigned short* updb = kb;
    unsigned short* hib  = vb;

    dim3 blk(256);

    // prep
    cast_f2b<<<dim3(7168), blk, 0, stream>>>(nodes, nodes_b, 7340032);
    tcast_all<<<dim3(32, 64, 9), blk, 0, stream>>>(Wq, Wk, Wv, We1, Wu1, Wu2, Wi1,
                                                   WT_all, Wu1T, Wu2T, Wi1T);
    build_bias<<<dim3(20), blk, 0, stream>>>(bq, bk, bv, bias_all, acc);

    // fused q|k|v|la|rb : N=5120, segmented bf16 out into qb..rbb
    gemm128w32<<<dim3(40, 56), blk, 0, stream>>>(
        nodes_b, 0, nullptr, 0, WT_all, 1024, bias_all, nullptr,
        nullptr, qb, BIG, 1024, 0);

    // cc = nodes[:,-1] @ Wc + be1 (fp32 out), WcT at WT_all row 5120
    gemm64x128<<<dim3(8, 16), blk, 0, stream>>>(
        nodes_b, 1, nullptr, 0, WT_all + (size_t)5120 * 1024, 1024, be1, nullptr,
        ccf, nullptr, 1024, 0);

    // attention + messages (msg overwrites la)
    attn_msg_b<<<dim3(7168), blk, 0, stream>>>(qb, kb, vb, lab, rbb, ccf, We2, be2,
                                               attn_o, msgb);

    // h_u = gelu([nodes|msg] @ Wu1 + bu1)
    gemm128w32<<<dim3(8, 56), blk, 0, stream>>>(
        nodes_b, 0, msgb, 0, Wu1T, 2048, bu1, nullptr, nullptr, hub, 0, 2048, 1);
    // updated = h_u @ Wu2 + bu2 + nodes (fp32 out + bf16 copy)
    gemm128w32<<<dim3(8, 56), blk, 0, stream>>>(
        hub, 0, nullptr, 0, Wu2T, 1024, bu2, nodes, upd_o, updb, 0, 1024, 0);
    // h_i = gelu([updated|ctx] @ Wi1 + bi1)
    gemm128w32<<<dim3(8, 56), blk, 0, stream>>>(
        updb, 0, updb, 2, Wi1T, 2048, bi1, nullptr, nullptr, hib, 0, 2048, 1);

    // tail
    row_dot_b<<<dim3(7168), blk, 0, stream>>>(hib, Wi2, bi2, il);
    imp_fused_k<<<dim3(1024), blk, 0, stream>>>(il, upd_o, imp_o, fused_o);
    physics_k<<<dim3(1024), blk, 0, stream>>>(upd_o, fused_o, acc);
    finalize_k<<<1, 1, 0, stream>>>(acc, phys_o, align_o);
}

// Round 6
// 580.170 us; speedup vs baseline: 1.0010x; 1.0010x over previous
//
#include <hip/hip_runtime.h>
#include <hip/hip_bf16.h>

// PhysicsGraphFusion: B=1024, N=7, D=1024
// Outputs (flat): fused (B*D), updated (B*N*D), imp (B*N), attn (B*N*N), phys (1), align (1)

typedef __attribute__((ext_vector_type(8))) short bf16x8;
typedef __attribute__((ext_vector_type(4))) float f32x4;
typedef __attribute__((ext_vector_type(16))) float f32x16;

__constant__ float c_adj[49] = {
    1,1,0,0,1,1,1,
    1,1,1,1,1,1,1,
    0,1,1,0,1,0,1,
    0,1,0,1,1,1,1,
    1,1,1,1,1,1,1,
    1,1,0,1,1,1,1,
    1,1,1,1,1,1,1};

// gelu via Abramowitz-Stegun 7.1.26 erf (|err| < 1.5e-7, ~12 VALU ops).
__device__ __forceinline__ float gelu_f(float x) {
    float z = fabsf(x) * 0.70710678118654752f;
    float t = 1.0f / (1.0f + 0.3275911f * z);
    float poly = ((((1.061405429f * t - 1.453152027f) * t + 1.421413741f) * t
                  - 0.284496736f) * t + 0.254829592f) * t;
    float e = __expf(-z * z);
    float erf_abs = 1.0f - poly * e;
    float erf = copysignf(erf_abs, x);
    return 0.5f * x * (1.0f + erf);
}
__device__ __forceinline__ float b2f(unsigned short u) {
    unsigned int x = ((unsigned int)u) << 16;
    union { unsigned int i; float f; } c; c.i = x; return c.f;
}
__device__ __forceinline__ unsigned short f2b(float f) {
    __hip_bfloat16 h = __float2bfloat16(f);
    union { __hip_bfloat16 b; unsigned short u; } c; c.b = h; return c.u;
}

__device__ __forceinline__ void gload_lds16(const void* g, void* l) {
    __builtin_amdgcn_global_load_lds(
        (const __attribute__((address_space(1))) unsigned int*)g,
        (__attribute__((address_space(3))) unsigned int*)l, 16, 0, 0);
}

// row mapping: 0: r->r ; 1: r->r*7+6 (ctx rows) ; 2: r->r-r%7+6 (ctx broadcast)
__device__ __forceinline__ int maprow(int r, int mode) {
    if (mode == 1) return r * 7 + 6;
    if (mode == 2) return r - r % 7 + 6;
    return r;
}

// ---------------------------------------------------------------------------
// 128x128-tile, 4-wave (256-thread) bf16 MFMA GEMM using 32x32x16 MFMA,
// 3-slot LDS ring, counted vmcnt.
//
// CONFLICT-FIX (R5 post-mortem): the 32-row fragment read with chunk
// swizzle X(row)=(row>>1)&3 measured 9.17M bank conflicts (4 cyc/read):
// stride-8 lane sets {p,p+8,..} share (row>>1)&3 (rows 8 apart) -> 4 lanes
// on 2 bank-quads. New swizzle X(row) = ((row>>1)^(row>>3))&3 is uniform
// 2-lanes/quad under BOTH consecutive-16 grouping (each quad exactly 2x,
// enumerated) and stride-8 grouping ((row>>3)&3 cycles all 4 values).
// Chunk stored at LDS pos ch = glb_chunk ^ X(row); pure permutation.
//
// MFMA 32x32x16: A/B = 8 bf16 (4 VGPR), row=lane&31, k=(lane>>5)*8+i;
// C/D = 16 f32, col=lane&31, row=(reg&3)+8*(reg>>2)+4*(lane>>5)
// [HW-verified by R5 passing].
//
// Ring: 3 slots x (128x32) per operand = 48 KB LDS. Iter kt: issue
// stage(kt+2) -> ds_read frags(kt) -> 8 MFMA (compiler-managed lgkmcnt) ->
// vmcnt(4) [tail vmcnt(0)] -> s_barrier. Race proof: iter kt reads slot
// kt%3, writes slot (kt+2)%3 (distinct mod 3); slot written at kt was last
// read at iter kt-1, sealed by that iter's barrier.
// XCD swizzle: bijective (grids 2240, 448 both % 8 == 0).
// ---------------------------------------------------------------------------
__global__ __launch_bounds__(256) void gemm128w32(
    const unsigned short* __restrict__ A1, int a1Mode,
    const unsigned short* __restrict__ A2, int a2Mode,
    const unsigned short* __restrict__ WT, int ldw,
    const float* __restrict__ bias,
    const float* __restrict__ resid,
    float* __restrict__ Cf,
    unsigned short* __restrict__ Cb, size_t segStride,
    int K, int act)
{
    __shared__ short As[3][128 * 32];
    __shared__ short Bs[3][128 * 32];
    const int tid = threadIdx.x;
    const int lane = tid & 63;
    const int w = tid >> 6;            // 4 waves (2x2)
    const int wr = (w >> 1) * 64;
    const int wc = (w & 1) * 64;

    // bijective XCD swizzle
    int lin = blockIdx.y * gridDim.x + blockIdx.x;
    const int nwg = gridDim.x * gridDim.y;
    const int cpx = nwg >> 3;
    lin = (lin & 7) * cpx + (lin >> 3);
    const int row0 = (lin / gridDim.x) * 128;
    const int col0 = (lin % gridDim.x) * 128;

    const int l31 = lane & 31;
    const int hi  = lane >> 5;
    const int xorv = ((l31 >> 1) ^ (l31 >> 3)) & 3;   // conflict-free swizzle
    // per-lane LDS offsets (shorts)
    int aRow[2], bRow[2], cOff[2];
    aRow[0] = (wr + l31) * 32;       aRow[1] = (wr + 32 + l31) * 32;
    bRow[0] = (wc + l31) * 32;       bRow[1] = (wc + 32 + l31) * 32;
    cOff[0] = ((hi)     ^ xorv) * 8;
    cOff[1] = ((2 + hi) ^ xorv) * 8;

    const int NTt = K >> 5;

    auto stage = [&](int ktn) {
        int k0n = ktn * 32;
        const unsigned short* srcA; int mode; int kbase;
        if (k0n < 1024) { srcA = A1; mode = a1Mode; kbase = k0n; }
        else            { srcA = A2; mode = a2Mode; kbase = k0n - 1024; }
        int slot = ktn % 3;
        #pragma unroll
        for (int rnd = 0; rnd < 2; ++rnd) {
            int c2 = rnd * 256 + tid;
            int m = c2 >> 2, ch = c2 & 3;
            int kc = (ch ^ (((m >> 1) ^ (m >> 3)) & 3)) * 8;  // pre-swizzled glb chunk
            int rr = maprow(row0 + m, mode);
            gload_lds16(srcA + (size_t)rr * 1024 + kbase + kc, &As[slot][c2 * 8]);
        }
        #pragma unroll
        for (int rnd = 0; rnd < 2; ++rnd) {
            int c2 = rnd * 256 + tid;
            int n = c2 >> 2, ch = c2 & 3;
            int kc = (ch ^ (((n >> 1) ^ (n >> 3)) & 3)) * 8;
            gload_lds16(WT + (size_t)(col0 + n) * ldw + k0n + kc, &Bs[slot][c2 * 8]);
        }
    };

    f32x16 acc[2][2] = {};

    // prologue: stage tiles 0,1; wait tile 0 (vmcnt(4): tile 1 in flight)
    stage(0);
    if (NTt > 1) stage(1);
    asm volatile("s_waitcnt vmcnt(4)" ::: "memory");
    asm volatile("s_barrier" ::: "memory");

    for (int kt = 0; kt < NTt; ++kt) {
        const short* Ab = &As[kt % 3][0];
        const short* Bb = &Bs[kt % 3][0];

        if (kt + 2 < NTt) stage(kt + 2);   // 2-tile lookahead

        bf16x8 af[2][2], bfv[2][2];
        #pragma unroll
        for (int ks = 0; ks < 2; ++ks) {
            #pragma unroll
            for (int mf = 0; mf < 2; ++mf)
                af[mf][ks] = *(const bf16x8*)(Ab + aRow[mf] + cOff[ks]);
            #pragma unroll
            for (int nf = 0; nf < 2; ++nf)
                bfv[nf][ks] = *(const bf16x8*)(Bb + bRow[nf] + cOff[ks]);
        }

        __builtin_amdgcn_s_setprio(1);
        #pragma unroll
        for (int ks = 0; ks < 2; ++ks)
            #pragma unroll
            for (int mf = 0; mf < 2; ++mf)
                #pragma unroll
                for (int nf = 0; nf < 2; ++nf)
                    acc[mf][nf] = __builtin_amdgcn_mfma_f32_32x32x16_bf16(
                        af[mf][ks], bfv[nf][ks], acc[mf][nf], 0, 0, 0);
        __builtin_amdgcn_s_setprio(0);

        if (kt < NTt - 2) asm volatile("s_waitcnt vmcnt(4)" ::: "memory");
        else              asm volatile("s_waitcnt vmcnt(0)" ::: "memory");
        asm volatile("s_barrier" ::: "memory");
    }

    // epilogue: C/D layout col=lane&31, row=(reg&3)+8*(reg>>2)+4*hi
    #pragma unroll
    for (int mf = 0; mf < 2; ++mf) {
        #pragma unroll
        for (int nf = 0; nf < 2; ++nf) {
            int c = col0 + wc + nf * 32 + l31;
            float bv = bias ? bias[c] : 0.0f;
            int seg = c >> 10, c0 = c & 1023;
            #pragma unroll
            for (int r = 0; r < 16; ++r) {
                int row = row0 + wr + mf * 32 + (r & 3) + 8 * (r >> 2) + 4 * hi;
                float vv = acc[mf][nf][r] + bv;
                if (act) vv = gelu_f(vv);
                if (resid) vv += resid[(size_t)row * 1024 + c];
                if (Cf) Cf[(size_t)row * 1024 + c] = vv;
                if (Cb) Cb[(size_t)seg * segStride + (size_t)row * 1024 + c0] = f2b(vv);
            }
        }
    }
}

// ---------------------------------------------------------------------------
// 64x128-tile bf16 MFMA GEMM (only used for the small ctx GEMM).
// ---------------------------------------------------------------------------
__global__ __launch_bounds__(256) void gemm64x128(
    const unsigned short* __restrict__ A1, int a1Mode,
    const unsigned short* __restrict__ A2, int a2Mode,
    const unsigned short* __restrict__ WT, int ldw,
    const float* __restrict__ bias,
    const float* __restrict__ resid,
    float* __restrict__ Cf,
    unsigned short* __restrict__ Cb,
    int K, int act)
{
    __shared__ short As[64 * 32];
    __shared__ short Bs[128 * 32];
    const int tid = threadIdx.x;
    const int lane = tid & 63;
    const int w = tid >> 6;
    const int wc = w * 32;
    const int row0 = blockIdx.y * 64;
    const int col0 = blockIdx.x * 128;
    const int fr = lane & 15;
    const int fko = (((lane >> 4) ^ ((fr >> 1) & 3)) << 3);

    f32x4 acc[4][2] = {};

    for (int k0 = 0; k0 < K; k0 += 32) {
        const unsigned short* srcA; int mode; int kbase;
        if (k0 < 1024) { srcA = A1; mode = a1Mode; kbase = k0; }
        else           { srcA = A2; mode = a2Mode; kbase = k0 - 1024; }
        {
            int m = tid >> 2, ch = tid & 3;
            int kc = (ch ^ ((m >> 1) & 3)) * 8;
            int rr = maprow(row0 + m, mode);
            gload_lds16(srcA + (size_t)rr * 1024 + kbase + kc, &As[tid * 8]);
        }
        #pragma unroll
        for (int rnd = 0; rnd < 2; ++rnd) {
            int c = rnd * 256 + tid;
            int n = c >> 2, ch = c & 3;
            int kc = (ch ^ ((n >> 1) & 3)) * 8;
            gload_lds16(WT + (size_t)(col0 + n) * ldw + k0 + kc, &Bs[c * 8]);
        }
        __syncthreads();
        bf16x8 af[4], bf_[2];
        #pragma unroll
        for (int i = 0; i < 4; ++i)
            af[i] = *(const bf16x8*)(&As[(i * 16 + fr) * 32 + fko]);
        #pragma unroll
        for (int j = 0; j < 2; ++j)
            bf_[j] = *(const bf16x8*)(&Bs[(wc + j * 16 + fr) * 32 + fko]);
        #pragma unroll
        for (int i = 0; i < 4; ++i)
            #pragma unroll
            for (int j = 0; j < 2; ++j)
                acc[i][j] = __builtin_amdgcn_mfma_f32_16x16x32_bf16(
                    af[i], bf_[j], acc[i][j], 0, 0, 0);
        __syncthreads();
    }

    const int qrow = (lane >> 4) * 4;
    const int qcol = lane & 15;
    #pragma unroll
    for (int i = 0; i < 4; ++i) {
        int rbase = row0 + i * 16 + qrow;
        #pragma unroll
        for (int j = 0; j < 2; ++j) {
            int c = col0 + wc + j * 16 + qcol;
            float bv = bias ? bias[c] : 0.0f;
            #pragma unroll
            for (int reg = 0; reg < 4; ++reg) {
                int r = rbase + reg;
                float vv = acc[i][j][reg] + bv;
                if (act) vv = gelu_f(vv);
                if (resid) vv += resid[(size_t)r * 1024 + c];
                if (Cf) Cf[(size_t)r * 1024 + c] = vv;
                if (Cb) Cb[(size_t)r * 1024 + c] = f2b(vv);
            }
        }
    }
}

// fp32 -> bf16 elementwise cast
__global__ __launch_bounds__(256) void cast_f2b(
    const float* __restrict__ in, unsigned short* __restrict__ out, int n)
{
    int i = (blockIdx.x * 256 + threadIdx.x) * 4;
    if (i >= n) return;
    float4 v = *(const float4*)(in + i);
    ushort4 o;
    o.x = f2b(v.x); o.y = f2b(v.y); o.z = f2b(v.z); o.w = f2b(v.w);
    *(ushort4*)(out + i) = o;
}

// All weight transposes+casts in one dispatch. grid (32, 64, 9).
__global__ __launch_bounds__(256) void tcast_all(
    const float* __restrict__ Wq, const float* __restrict__ Wk,
    const float* __restrict__ Wv, const float* __restrict__ We1,
    const float* __restrict__ Wu1, const float* __restrict__ Wu2,
    const float* __restrict__ Wi1,
    unsigned short* __restrict__ WT_all, unsigned short* __restrict__ Wu1T,
    unsigned short* __restrict__ Wu2T, unsigned short* __restrict__ Wi1T)
{
    const int z = blockIdx.z;
    const float* src; unsigned short* dst; int R;
    switch (z) {
        case 0: src = Wq;            dst = WT_all;               R = 1024; break;
        case 1: src = Wk;            dst = WT_all + 1024 * 1024; R = 1024; break;
        case 2: src = Wv;            dst = WT_all + 2048 * 1024; R = 1024; break;
        case 3: src = We1;           dst = WT_all + 3072 * 1024; R = 1024; break;
        case 4: src = We1 + 1048576; dst = WT_all + 4096 * 1024; R = 1024; break;
        case 5: src = We1 + 2097152; dst = WT_all + 5120 * 1024; R = 1024; break;
        case 6: src = Wu1;           dst = Wu1T;                 R = 2048; break;
        case 7: src = Wu2;           dst = Wu2T;                 R = 1024; break;
        default: src = Wi1;          dst = Wi1T;                 R = 2048; break;
    }
    const int rt = blockIdx.y * 32;
    if (rt >= R) return;
    const int ct = blockIdx.x * 32;
    __shared__ float t[32][33];
    const int tx = threadIdx.x & 31, ty = threadIdx.x >> 5;
    #pragma unroll
    for (int s = 0; s < 4; ++s)
        t[ty + s * 8][tx] = src[(size_t)(rt + ty + s * 8) * 1024 + ct + tx];
    __syncthreads();
    #pragma unroll
    for (int s = 0; s < 4; ++s)
        dst[(size_t)(ct + ty + s * 8) * R + rt + tx] = f2b(t[tx][ty + s * 8]);
}

// bias_all[5120] = [bq | bk | bv | 0 | 0]; also zeroes the accum scratch
__global__ void build_bias(const float* __restrict__ bq,
                           const float* __restrict__ bk,
                           const float* __restrict__ bv,
                           float* __restrict__ bias_all,
                           float* __restrict__ acc)
{
    int i = blockIdx.x * 256 + threadIdx.x;
    if (i < 4) acc[i] = 0.f;
    if (i >= 5120) return;
    int seg = i >> 10, c = i & 1023;
    float v = 0.f;
    if (seg == 0) v = bq[c];
    else if (seg == 1) v = bk[c];
    else if (seg == 2) v = bv[c];
    bias_all[i] = v;
}

// ---------------------------------------------------------------------------
// One block per (b,n): edge MLP + logits + softmax + messages (bf16 in/out).
// All 7 m-partials in registers -> one reduction phase (2 barriers).
// msg may alias la (each block reads only its own la row, into regs first).
// ---------------------------------------------------------------------------
__global__ __launch_bounds__(256) void attn_msg_b(
    const unsigned short* __restrict__ q, const unsigned short* __restrict__ k,
    const unsigned short* __restrict__ v,
    const unsigned short* __restrict__ la, const unsigned short* __restrict__ rb,
    const float* __restrict__ cc,
    const float* __restrict__ We2, const float* __restrict__ be2,
    float* __restrict__ attn_out, unsigned short* __restrict__ msg)
{
    const int bn = blockIdx.x;
    const int b = bn / 7, n = bn % 7;
    const int tid = threadIdx.x;
    const int lane = tid & 63, wv = tid >> 6;
    const int d0 = tid * 4;
    __shared__ float red[4][14];
    __shared__ float sm[7];

    float qv[4], lav[4], wev[4];
    {
        ushort4 q4 = *(const ushort4*)(q + (size_t)bn * 1024 + d0);
        ushort4 l4 = *(const ushort4*)(la + (size_t)bn * 1024 + d0);
        float4 c4 = *(const float4*)(cc + (size_t)b * 1024 + d0);
        float4 w4 = *(const float4*)(We2 + d0);
        qv[0] = b2f(q4.x); qv[1] = b2f(q4.y); qv[2] = b2f(q4.z); qv[3] = b2f(q4.w);
        lav[0] = b2f(l4.x) + c4.x; lav[1] = b2f(l4.y) + c4.y;
        lav[2] = b2f(l4.z) + c4.z; lav[3] = b2f(l4.w) + c4.w;
        wev[0] = w4.x; wev[1] = w4.y; wev[2] = w4.z; wev[3] = w4.w;
    }

    float s1a[7], s2a[7];
    #pragma unroll
    for (int m = 0; m < 7; ++m) {
        ushort4 k4 = *(const ushort4*)(k  + (size_t)(b * 7 + m) * 1024 + d0);
        ushort4 r4 = *(const ushort4*)(rb + (size_t)(b * 7 + m) * 1024 + d0);
        s1a[m] = qv[0] * b2f(k4.x) + qv[1] * b2f(k4.y)
               + qv[2] * b2f(k4.z) + qv[3] * b2f(k4.w);
        s2a[m] = gelu_f(lav[0] + b2f(r4.x)) * wev[0]
               + gelu_f(lav[1] + b2f(r4.y)) * wev[1]
               + gelu_f(lav[2] + b2f(r4.z)) * wev[2]
               + gelu_f(lav[3] + b2f(r4.w)) * wev[3];
    }
    #pragma unroll
    for (int m = 0; m < 7; ++m) {
        float x1 = s1a[m], x2 = s2a[m];
        #pragma unroll
        for (int off = 32; off > 0; off >>= 1) {
            x1 += __shfl_down(x1, off);
            x2 += __shfl_down(x2, off);
        }
        if (lane == 0) { red[wv][m] = x1; red[wv][7 + m] = x2; }
    }
    __syncthreads();
    if (tid == 0) {
        float l[7];
        #pragma unroll
        for (int m = 0; m < 7; ++m) {
            float d1 = red[0][m] + red[1][m] + red[2][m] + red[3][m];
            float d2 = red[0][7 + m] + red[1][7 + m] + red[2][7 + m] + red[3][7 + m];
            l[m] = d1 * (1.0f / 32.0f) + d2 + be2[0]
                 + (c_adj[n * 7 + m] - 1.0f) * 10000.0f;
        }
        float mx = l[0];
        #pragma unroll
        for (int m = 1; m < 7; ++m) mx = fmaxf(mx, l[m]);
        float e[7], s = 0.f;
        #pragma unroll
        for (int m = 0; m < 7; ++m) { e[m] = __expf(l[m] - mx); s += e[m]; }
        float inv = 1.0f / s;
        #pragma unroll
        for (int m = 0; m < 7; ++m) {
            float wgt = e[m] * inv;
            sm[m] = wgt;
            attn_out[(size_t)bn * 7 + m] = wgt;
        }
    }
    __syncthreads();
    float wr_[7];
    #pragma unroll
    for (int m = 0; m < 7; ++m) wr_[m] = sm[m];
    float s0 = 0.f, s1 = 0.f, s2 = 0.f, s3 = 0.f;
    #pragma unroll
    for (int m = 0; m < 7; ++m) {
        ushort4 v4 = *(const ushort4*)(v + (size_t)(b * 7 + m) * 1024 + d0);
        s0 += wr_[m] * b2f(v4.x); s1 += wr_[m] * b2f(v4.y);
        s2 += wr_[m] * b2f(v4.z); s3 += wr_[m] * b2f(v4.w);
    }
    ushort4 o;
    o.x = f2b(s0); o.y = f2b(s1); o.z = f2b(s2); o.w = f2b(s3);
    *(ushort4*)(msg + (size_t)bn * 1024 + d0) = o;
}

// imp_logits[r] = dot(H[r,:], w2) + b2[0]   (H bf16)
__global__ __launch_bounds__(256) void row_dot_b(
    const unsigned short* __restrict__ H, const float* __restrict__ w2,
    const float* __restrict__ b2, float* __restrict__ out)
{
    const int r = blockIdx.x;
    const int tid = threadIdx.x;
    const int lane = tid & 63, wv = tid >> 6;
    __shared__ float red[4];
    const int d0 = tid * 4;
    ushort4 h4 = *(const ushort4*)(H + (size_t)r * 1024 + d0);
    float4 w4 = *(const float4*)(w2 + d0);
    float s = b2f(h4.x) * w4.x + b2f(h4.y) * w4.y
            + b2f(h4.z) * w4.z + b2f(h4.w) * w4.w;
    #pragma unroll
    for (int off = 32; off > 0; off >>= 1) s += __shfl_down(s, off);
    if (lane == 0) red[wv] = s;
    __syncthreads();
    if (tid == 0) out[r] = red[0] + red[1] + red[2] + red[3] + b2[0];
}

// ---------------------------------------------------------------------------
// Fused tail: per-b softmax/cap/imp + fused = sum_n imp*upd + physics
// partials. upd is read ONCE (was twice: imp_fused_k + physics_k); fused
// stays in LDS for the physics pass.
// ---------------------------------------------------------------------------
__global__ __launch_bounds__(256) void imp_phys_k(
    const float* __restrict__ logits, const float* __restrict__ upd,
    float* __restrict__ imp_out, float* __restrict__ fused_out,
    float* __restrict__ accums)
{
    const int b = blockIdx.x;
    const int tid = threadIdx.x;
    const int lane = tid & 63, wv = tid >> 6;
    __shared__ float u[7][1024];
    __shared__ float f[1024];
    __shared__ float wsh[7];
    __shared__ float wred[4][36];

    for (int idx = tid; idx < 7 * 1024; idx += 256)
        u[idx >> 10][idx & 1023] = upd[(size_t)b * 7168 + idx];

    if (tid == 0) {
        float l[7], e[7];
        float mx = -1e30f;
        for (int i = 0; i < 7; ++i) { l[i] = logits[b * 7 + i]; mx = fmaxf(mx, l[i]); }
        float s = 0.f;
        for (int i = 0; i < 7; ++i) { e[i] = expf(l[i] - mx); s += e[i]; }
        float inv = 1.0f / s;
        float imp[7];
        for (int i = 0; i < 7; ++i) imp[i] = e[i] * inv;
        const float cap[7] = {1.f, 1.f, 1.f, 0.26f, 1.f, 1.f, 0.24f};
        const float fr[7]  = {1.f, 1.f, 1.f, 0.f,   1.f, 1.f, 0.f};
        float capped[7], capsum = 0.f, fmass = 0.f;
        for (int i = 0; i < 7; ++i) {
            capped[i] = fminf(imp[i], cap[i]);
            capsum += capped[i];
            fmass += imp[i] * fr[i];
        }
        float residual = fmaxf(1.0f - capsum, 0.0f);
        float redis[7], rs = 0.f;
        for (int i = 0; i < 7; ++i) {
            float fs = (fmass > 1e-6f) ? imp[i] * fr[i] / fmaxf(fmass, 1e-6f)
                                       : fr[i] * 0.2f;
            redis[i] = capped[i] + fs * residual;
            rs += redis[i];
        }
        float invr = 1.0f / fmaxf(rs, 1e-6f);
        for (int i = 0; i < 7; ++i) {
            float wi = redis[i] * invr;
            wsh[i] = wi;
            imp_out[b * 7 + i] = wi;
        }
    }
    __syncthreads();

    float wr[7];
    #pragma unroll
    for (int i = 0; i < 7; ++i) wr[i] = wsh[i];
    #pragma unroll
    for (int j = 0; j < 4; ++j) {
        int d = tid + j * 256;
        float s = 0.f;
        #pragma unroll
        for (int nn2 = 0; nn2 < 7; ++nn2)
            s += wr[nn2] * u[nn2][d];
        f[d] = s;
        fused_out[(size_t)b * 1024 + d] = s;
    }
    __syncthreads();

    float vals[36];
    #pragma unroll
    for (int i = 0; i < 36; ++i) vals[i] = 0.f;
    for (int d = tid; d < 1024; d += 256) {
        float x[7];
        #pragma unroll
        for (int n = 0; n < 7; ++n) x[n] = u[n][d];
        float fv = f[d];
        int idx = 0;
        #pragma unroll
        for (int n = 0; n < 7; ++n) {
            #pragma unroll
            for (int m = n; m < 7; ++m) vals[idx++] += x[n] * x[m];
        }
        #pragma unroll
        for (int n = 0; n < 7; ++n) vals[28 + n] += x[n] * fv;
        vals[35] += fv * fv;
    }
    #pragma unroll
    for (int i = 0; i < 36; ++i) {
        float s = vals[i];
        #pragma unroll
        for (int off = 32; off > 0; off >>= 1) s += __shfl_down(s, off);
        if (lane == 0) wred[wv][i] = s;
    }
    __syncthreads();
    if (tid == 0) {
        float tv[36];
        for (int i = 0; i < 36; ++i)
            tv[i] = wred[0][i] + wred[1][i] + wred[2][i] + wred[3][i];
        auto didx = [](int n, int m) -> int {
            if (n > m) { int t = n; n = m; m = t; }
            return n * 7 - n * (n - 1) / 2 + (m - n);
        };
        float norms[7];
        for (int n = 0; n < 7; ++n) norms[n] = sqrtf(tv[didx(n, n)]);
        float e = 0.f, nl = 0.f;
        for (int n = 0; n < 7; ++n)
            for (int m = 0; m < 7; ++m) {
                float cos_ = tv[didx(n, m)] / fmaxf(norms[n] * norms[m], 1e-8f);
                float adj = c_adj[n * 7 + m];
                e += (1.0f - cos_) * adj;
                if (adj == 0.0f && n != m) nl += fmaxf(cos_ - 0.35f, 0.0f);
            }
        float fnorm = sqrtf(tv[35]);
        float al = 0.f;
        for (int n = 0; n < 7; ++n) {
            float cosn = tv[28 + n] /
                         (fmaxf(norms[n], 1e-12f) * fmaxf(fnorm, 1e-12f));
            al += 1.0f - cosn;
        }
        atomicAdd(&accums[0], e);
        atomicAdd(&accums[1], nl);
        atomicAdd(&accums[2], al);
    }
}

__global__ void finalize_k(const float* __restrict__ a,
                           float* __restrict__ phys_o,
                           float* __restrict__ align_o)
{
    phys_o[0]  = a[0] / 41.0f + 0.5f * (a[1] / 8.0f);
    align_o[0] = a[2] * (1.0f / 7168.0f);
}

extern "C" void kernel_launch(void* const* d_in, const int* in_sizes, int n_in,
                              void* d_out, int out_size, void* d_ws, size_t ws_size,
                              hipStream_t stream)
{
    const float* nodes = (const float*)d_in[0];
    const float* Wq  = (const float*)d_in[1];
    const float* bq  = (const float*)d_in[2];
    const float* Wk  = (const float*)d_in[3];
    const float* bk  = (const float*)d_in[4];
    const float* Wv  = (const float*)d_in[5];
    const float* bv  = (const float*)d_in[6];
    const float* We1 = (const float*)d_in[7];
    const float* be1 = (const float*)d_in[8];
    const float* We2 = (const float*)d_in[9];
    const float* be2 = (const float*)d_in[10];
    const float* Wu1 = (const float*)d_in[11];
    const float* bu1 = (const float*)d_in[12];
    const float* Wu2 = (const float*)d_in[13];
    const float* bu2 = (const float*)d_in[14];
    const float* Wi1 = (const float*)d_in[15];
    const float* bi1 = (const float*)d_in[16];
    const float* Wi2 = (const float*)d_in[17];
    const float* bi2 = (const float*)d_in[18];

    float* out = (float*)d_out;
    float* fused_o = out;                            // 1,048,576
    float* upd_o   = out + 1048576;                  // 7,340,032
    float* imp_o   = out + 1048576 + 7340032;        // 7,168
    float* attn_o  = imp_o + 7168;                   // 50,176
    float* phys_o  = attn_o + 50176;                 // 1
    float* align_o = phys_o + 1;                     // 1

    const size_t BIG = 7340032;   // B*N*D
    const size_t MEG = 1048576;   // D*D
    char* p = (char*)d_ws;
    unsigned short* nodes_b = (unsigned short*)p; p += BIG * 2;
    unsigned short* qb      = (unsigned short*)p; p += BIG * 2;   // seg 0; reused: h_u
    unsigned short* kb      = (unsigned short*)p; p += BIG * 2;   // seg 1; reused: upd_b
    unsigned short* vb      = (unsigned short*)p; p += BIG * 2;   // seg 2; reused: h_i
    unsigned short* lab     = (unsigned short*)p; p += BIG * 2;   // seg 3; reused: msg
    unsigned short* rbb     = (unsigned short*)p; p += BIG * 2;   // seg 4
    unsigned short* WT_all  = (unsigned short*)p; p += (size_t)6144 * 1024 * 2;
    unsigned short* Wu1T    = (unsigned short*)p; p += 2 * MEG * 2;
    unsigned short* Wu2T    = (unsigned short*)p; p += MEG * 2;
    unsigned short* Wi1T    = (unsigned short*)p; p += 2 * MEG * 2;
    float* bias_all = (float*)p; p += 5120 * 4;
    float* ccf = (float*)p; p += MEG * 4;
    float* il  = (float*)p; p += 7168 * 4;
    float* acc = (float*)p; p += 4 * 4;
    unsigned short* msgb = lab;   // alias: safe (see attn_msg_b)
    unsigned short* hub  = qb;
    unsigned short* updb = kb;
    unsigned short* hib  = vb;

    dim3 blk(256);

    // prep
    cast_f2b<<<dim3(7168), blk, 0, stream>>>(nodes, nodes_b, 7340032);
    tcast_all<<<dim3(32, 64, 9), blk, 0, stream>>>(Wq, Wk, Wv, We1, Wu1, Wu2, Wi1,
                                                   WT_all, Wu1T, Wu2T, Wi1T);
    build_bias<<<dim3(20), blk, 0, stream>>>(bq, bk, bv, bias_all, acc);

    // fused q|k|v|la|rb : N=5120, segmented bf16 out into qb..rbb
    gemm128w32<<<dim3(40, 56), blk, 0, stream>>>(
        nodes_b, 0, nullptr, 0, WT_all, 1024, bias_all, nullptr,
        nullptr, qb, BIG, 1024, 0);

    // cc = nodes[:,-1] @ Wc + be1 (fp32 out), WcT at WT_all row 5120
    gemm64x128<<<dim3(8, 16), blk, 0, stream>>>(
        nodes_b, 1, nullptr, 0, WT_all + (size_t)5120 * 1024, 1024, be1, nullptr,
        ccf, nullptr, 1024, 0);

    // attention + messages (msg overwrites la)
    attn_msg_b<<<dim3(7168), blk, 0, stream>>>(qb, kb, vb, lab, rbb, ccf, We2, be2,
                                               attn_o, msgb);

    // h_u = gelu([nodes|msg] @ Wu1 + bu1)
    gemm128w32<<<dim3(8, 56), blk, 0, stream>>>(
        nodes_b, 0, msgb, 0, Wu1T, 2048, bu1, nullptr, nullptr, hub, 0, 2048, 1);
    // updated = h_u @ Wu2 + bu2 + nodes (fp32 out + bf16 copy)
    gemm128w32<<<dim3(8, 56), blk, 0, stream>>>(
        hub, 0, nullptr, 0, Wu2T, 1024, bu2, nodes, upd_o, updb, 0, 1024, 0);
    // h_i = gelu([updated|ctx] @ Wi1 + bi1)
    gemm128w32<<<dim3(8, 56), blk, 0, stream>>>(
        updb, 0, updb, 2, Wi1T, 2048, bi1, nullptr, nullptr, hib, 0, 2048, 1);

    // tail
    row_dot_b<<<dim3(7168), blk, 0, stream>>>(hib, Wi2, bi2, il);
    imp_phys_k<<<dim3(1024), blk, 0, stream>>>(il, upd_o, imp_o, fused_o, acc);
    finalize_k<<<1, 1, 0, stream>>>(acc, phys_o, align_o);
}

// Round 7
// 539.136 us; speedup vs baseline: 1.0772x; 1.0761x over previous
//
#include <hip/hip_runtime.h>
#include <hip/hip_bf16.h>

// PhysicsGraphFusion: B=1024, N=7, D=1024
// Outputs (flat): fused (B*D), updated (B*N*D), imp (B*N), attn (B*N*N), phys (1), align (1)

typedef __attribute__((ext_vector_type(8))) short bf16x8;
typedef __attribute__((ext_vector_type(4))) float f32x4;

__constant__ float c_adj[49] = {
    1,1,0,0,1,1,1,
    1,1,1,1,1,1,1,
    0,1,1,0,1,0,1,
    0,1,0,1,1,1,1,
    1,1,1,1,1,1,1,
    1,1,0,1,1,1,1,
    1,1,1,1,1,1,1};

// gelu via Abramowitz-Stegun 7.1.26 erf (|err| < 1.5e-7, ~12 VALU ops).
__device__ __forceinline__ float gelu_f(float x) {
    float z = fabsf(x) * 0.70710678118654752f;
    float t = 1.0f / (1.0f + 0.3275911f * z);
    float poly = ((((1.061405429f * t - 1.453152027f) * t + 1.421413741f) * t
                  - 0.284496736f) * t + 0.254829592f) * t;
    float e = __expf(-z * z);
    float erf_abs = 1.0f - poly * e;
    float erf = copysignf(erf_abs, x);
    return 0.5f * x * (1.0f + erf);
}
__device__ __forceinline__ float b2f(unsigned short u) {
    unsigned int x = ((unsigned int)u) << 16;
    union { unsigned int i; float f; } c; c.i = x; return c.f;
}
__device__ __forceinline__ unsigned short f2b(float f) {
    __hip_bfloat16 h = __float2bfloat16(f);
    union { __hip_bfloat16 b; unsigned short u; } c; c.b = h; return c.u;
}

__device__ __forceinline__ void gload_lds16(const void* g, void* l) {
    __builtin_amdgcn_global_load_lds(
        (const __attribute__((address_space(1))) unsigned int*)g,
        (__attribute__((address_space(3))) unsigned int*)l, 16, 0, 0);
}

// row mapping: 0: r->r ; 1: r->r*7+6 (ctx rows) ; 2: r->r-r%7+6 (ctx broadcast)
__device__ __forceinline__ int maprow(int r, int mode) {
    if (mode == 1) return r * 7 + 6;
    if (mode == 2) return r - r % 7 + 6;
    return r;
}

// ---------------------------------------------------------------------------
// 128x128-tile double-buffered 4-wave bf16 MFMA GEMM (16x16x32 frags).
// PROVEN: R3 measured 122.3 us on the QKV shape, 0 bank conflicts.
// Used for the QKV GEMM (2240 blocks: occupancy less critical, lowest LDS
// traffic per block-K-tile: 32KB reads + 16KB stage).
// Per K-tile: issue stage(kt+1) FIRST -> ds_read frags(kt) -> 16 MFMA
// (compiler-managed lgkmcnt) -> vmcnt(0) AFTER MFMA (drain hidden under
// compute) -> one raw s_barrier. Race proof: writes to slot (kt+1)&1 are
// issued in iter kt, strictly after the barrier ending iter kt-1 which
// sealed all reads of that slot.
// Chunk swizzle (measured 0 conflicts): LDS chunk = glb chunk ^ ((row>>1)&3).
// XCD swizzle: bijective (grid 2240 % 8 == 0).
// ---------------------------------------------------------------------------
__global__ __launch_bounds__(256) void gemm128db(
    const unsigned short* __restrict__ A1, int a1Mode,
    const unsigned short* __restrict__ A2, int a2Mode,
    const unsigned short* __restrict__ WT, int ldw,
    const float* __restrict__ bias,
    const float* __restrict__ resid,
    float* __restrict__ Cf,
    unsigned short* __restrict__ Cb, size_t segStride,
    int K, int act)
{
    __shared__ short As[2][128 * 32];
    __shared__ short Bs[2][128 * 32];
    const int tid = threadIdx.x;
    const int lane = tid & 63;
    const int w = tid >> 6;
    const int wr = (w >> 1) * 64;
    const int wc = (w & 1) * 64;

    int lin = blockIdx.y * gridDim.x + blockIdx.x;
    const int nwg = gridDim.x * gridDim.y;
    const int cpx = nwg >> 3;
    lin = (lin & 7) * cpx + (lin >> 3);
    const int row0 = (lin / gridDim.x) * 128;
    const int col0 = (lin % gridDim.x) * 128;

    const int fr = lane & 15;
    const int fko = (((lane >> 4) ^ ((fr >> 1) & 3)) << 3);

    const int NTt = K >> 5;

    auto stage = [&](int ktn) {
        int k0n = ktn * 32;
        const unsigned short* srcA; int mode; int kbase;
        if (k0n < 1024) { srcA = A1; mode = a1Mode; kbase = k0n; }
        else            { srcA = A2; mode = a2Mode; kbase = k0n - 1024; }
        short* Adst = &As[ktn & 1][0];
        short* Bdst = &Bs[ktn & 1][0];
        #pragma unroll
        for (int rnd = 0; rnd < 2; ++rnd) {
            int c = rnd * 256 + tid;
            int m = c >> 2, ch = c & 3;
            int kc = (ch ^ ((m >> 1) & 3)) * 8;
            int rr = maprow(row0 + m, mode);
            gload_lds16(srcA + (size_t)rr * 1024 + kbase + kc, Adst + c * 8);
        }
        #pragma unroll
        for (int rnd = 0; rnd < 2; ++rnd) {
            int c = rnd * 256 + tid;
            int n = c >> 2, ch = c & 3;
            int kc = (ch ^ ((n >> 1) & 3)) * 8;
            gload_lds16(WT + (size_t)(col0 + n) * ldw + k0n + kc, Bdst + c * 8);
        }
    };

    f32x4 acc[4][4] = {};

    stage(0);
    asm volatile("s_waitcnt vmcnt(0)" ::: "memory");
    asm volatile("s_barrier" ::: "memory");

    for (int kt = 0; kt < NTt; ++kt) {
        const short* Ab = &As[kt & 1][0];
        const short* Bb = &Bs[kt & 1][0];

        if (kt + 1 < NTt) stage(kt + 1);

        bf16x8 af[4], bfv[4];
        #pragma unroll
        for (int i = 0; i < 4; ++i)
            af[i] = *(const bf16x8*)(Ab + (wr + i * 16 + fr) * 32 + fko);
        #pragma unroll
        for (int j = 0; j < 4; ++j)
            bfv[j] = *(const bf16x8*)(Bb + (wc + j * 16 + fr) * 32 + fko);

        __builtin_amdgcn_s_setprio(1);
        #pragma unroll
        for (int i = 0; i < 4; ++i)
            #pragma unroll
            for (int j = 0; j < 4; ++j)
                acc[i][j] = __builtin_amdgcn_mfma_f32_16x16x32_bf16(
                    af[i], bfv[j], acc[i][j], 0, 0, 0);
        __builtin_amdgcn_s_setprio(0);

        asm volatile("s_waitcnt vmcnt(0)" ::: "memory");
        asm volatile("s_barrier" ::: "memory");
    }

    const int qrow = (lane >> 4) * 4;
    const int qcol = lane & 15;
    #pragma unroll
    for (int i = 0; i < 4; ++i) {
        int rbase = row0 + wr + i * 16 + qrow;
        #pragma unroll
        for (int j = 0; j < 4; ++j) {
            int c = col0 + wc + j * 16 + qcol;
            float bv = bias ? bias[c] : 0.0f;
            int seg = c >> 10, c0 = c & 1023;
            #pragma unroll
            for (int reg = 0; reg < 4; ++reg) {
                int r = rbase + reg;
                float vv = acc[i][j][reg] + bv;
                if (act) vv = gelu_f(vv);
                if (resid) vv += resid[(size_t)r * 1024 + c];
                if (Cf) Cf[(size_t)r * 1024 + c] = vv;
                if (Cb) Cb[(size_t)seg * segStride + (size_t)r * 1024 + c0] = f2b(vv);
            }
        }
    }
}

// ---------------------------------------------------------------------------
// 128x128-tile, 8-wave (512-thread) bf16 MFMA GEMM, 3-slot ring, counted
// vmcnt. PROVEN in R4 (best total, high occupancy: regs <= 128 -> 4 w/SIMD).
// Used for the MLP GEMMs (448-block grids: occupancy-critical).
// NEW: optional fused row-dot epilogue (w2 != nullptr): instead of writing
// C, computes il[row] += sum_c gelu(C[row,c]) * w2[c] via 16-lane shfl
// reduce + LDS row-accumulate + 1 global atomicAdd per row per block.
// (h_i is consumed ONLY by the imp-logit dot; this removes a 30 MB write
// and a 30 MB read. bi2 is softmax-invariant and dropped.)
// ---------------------------------------------------------------------------
__global__ __launch_bounds__(512, 4) void gemm128x8w(
    const unsigned short* __restrict__ A1, int a1Mode,
    const unsigned short* __restrict__ A2, int a2Mode,
    const unsigned short* __restrict__ WT, int ldw,
    const float* __restrict__ bias,
    const float* __restrict__ resid,
    float* __restrict__ Cf,
    unsigned short* __restrict__ Cb, size_t segStride,
    int K, int act,
    const float* __restrict__ w2, float* __restrict__ ildst)
{
    __shared__ short As[3][128 * 32];
    __shared__ short Bs[3][128 * 32];
    const int tid = threadIdx.x;
    const int lane = tid & 63;
    const int w = tid >> 6;            // 8 waves
    const int wr = (w >> 2) * 64;      // 0,64
    const int wc = (w & 3) * 32;       // 0,32,64,96

    int lin = blockIdx.y * gridDim.x + blockIdx.x;
    const int nwg = gridDim.x * gridDim.y;
    const int cpx = nwg >> 3;
    lin = (lin & 7) * cpx + (lin >> 3);
    const int row0 = (lin / gridDim.x) * 128;
    const int col0 = (lin % gridDim.x) * 128;

    const int fr = lane & 15;
    const int fko = (((lane >> 4) ^ ((fr >> 1) & 3)) << 3);

    const int sm_ = tid >> 2, sch = tid & 3;
    const int skc = (sch ^ ((sm_ >> 1) & 3)) * 8;
    const int ldsoff = tid * 8;

    const int NTt = K >> 5;

    auto stage = [&](int ktn) {
        int k0n = ktn * 32;
        const unsigned short* srcA; int mode; int kbase;
        if (k0n < 1024) { srcA = A1; mode = a1Mode; kbase = k0n; }
        else            { srcA = A2; mode = a2Mode; kbase = k0n - 1024; }
        int slot = ktn % 3;
        int rr = maprow(row0 + sm_, mode);
        gload_lds16(srcA + (size_t)rr * 1024 + kbase + skc, &As[slot][ldsoff]);
        gload_lds16(WT + (size_t)(col0 + sm_) * ldw + k0n + skc, &Bs[slot][ldsoff]);
    };

    f32x4 acc[4][2] = {};

    stage(0);
    if (NTt > 1) stage(1);
    asm volatile("s_waitcnt vmcnt(2)" ::: "memory");
    asm volatile("s_barrier" ::: "memory");

    for (int kt = 0; kt < NTt; ++kt) {
        const short* Ab = &As[kt % 3][0];
        const short* Bb = &Bs[kt % 3][0];

        if (kt + 2 < NTt) stage(kt + 2);

        bf16x8 af[4], bfv[2];
        #pragma unroll
        for (int i = 0; i < 4; ++i)
            af[i] = *(const bf16x8*)(Ab + (wr + i * 16 + fr) * 32 + fko);
        #pragma unroll
        for (int j = 0; j < 2; ++j)
            bfv[j] = *(const bf16x8*)(Bb + (wc + j * 16 + fr) * 32 + fko);

        __builtin_amdgcn_s_setprio(1);
        #pragma unroll
        for (int i = 0; i < 4; ++i)
            #pragma unroll
            for (int j = 0; j < 2; ++j)
                acc[i][j] = __builtin_amdgcn_mfma_f32_16x16x32_bf16(
                    af[i], bfv[j], acc[i][j], 0, 0, 0);
        __builtin_amdgcn_s_setprio(0);

        if (kt < NTt - 2) asm volatile("s_waitcnt vmcnt(2)" ::: "memory");
        else              asm volatile("s_waitcnt vmcnt(0)" ::: "memory");
        asm volatile("s_barrier" ::: "memory");
    }

    const int qrow = (lane >> 4) * 4;
    const int qcol = lane & 15;

    if (w2) {
        // fused row-dot epilogue: il[row] += sum_c gelu(acc+bias) * w2[c]
        float* rowacc = (float*)&As[0][0];   // LDS reuse; all reads sealed
        if (tid < 128) rowacc[tid] = 0.f;
        __syncthreads();
        int c0 = col0 + wc + qcol;
        int c1 = col0 + wc + 16 + qcol;
        float b0 = bias[c0], b1 = bias[c1];
        float w20 = w2[c0], w21 = w2[c1];
        #pragma unroll
        for (int i = 0; i < 4; ++i) {
            #pragma unroll
            for (int reg = 0; reg < 4; ++reg) {
                float v = gelu_f(acc[i][0][reg] + b0) * w20
                        + gelu_f(acc[i][1][reg] + b1) * w21;
                // reduce over the 16 qcol lanes (consecutive lane ids)
                #pragma unroll
                for (int off = 8; off > 0; off >>= 1)
                    v += __shfl_down(v, off, 16);
                if (qcol == 0)
                    atomicAdd(&rowacc[wr + i * 16 + qrow + reg], v);
            }
        }
        __syncthreads();
        if (tid < 128) atomicAdd(&ildst[row0 + tid], rowacc[tid]);
        return;
    }

    #pragma unroll
    for (int i = 0; i < 4; ++i) {
        int rbase = row0 + wr + i * 16 + qrow;
        #pragma unroll
        for (int j = 0; j < 2; ++j) {
            int c = col0 + wc + j * 16 + qcol;
            float bv = bias ? bias[c] : 0.0f;
            int seg = c >> 10, c0 = c & 1023;
            #pragma unroll
            for (int reg = 0; reg < 4; ++reg) {
                int r = rbase + reg;
                float vv = acc[i][j][reg] + bv;
                if (act) vv = gelu_f(vv);
                if (resid) vv += resid[(size_t)r * 1024 + c];
                if (Cf) Cf[(size_t)r * 1024 + c] = vv;
                if (Cb) Cb[(size_t)seg * segStride + (size_t)r * 1024 + c0] = f2b(vv);
            }
        }
    }
}

// ---------------------------------------------------------------------------
// 64x128-tile bf16 MFMA GEMM (only used for the small ctx GEMM).
// ---------------------------------------------------------------------------
__global__ __launch_bounds__(256) void gemm64x128(
    const unsigned short* __restrict__ A1, int a1Mode,
    const unsigned short* __restrict__ A2, int a2Mode,
    const unsigned short* __restrict__ WT, int ldw,
    const float* __restrict__ bias,
    const float* __restrict__ resid,
    float* __restrict__ Cf,
    unsigned short* __restrict__ Cb,
    int K, int act)
{
    __shared__ short As[64 * 32];
    __shared__ short Bs[128 * 32];
    const int tid = threadIdx.x;
    const int lane = tid & 63;
    const int w = tid >> 6;
    const int wc = w * 32;
    const int row0 = blockIdx.y * 64;
    const int col0 = blockIdx.x * 128;
    const int fr = lane & 15;
    const int fko = (((lane >> 4) ^ ((fr >> 1) & 3)) << 3);

    f32x4 acc[4][2] = {};

    for (int k0 = 0; k0 < K; k0 += 32) {
        const unsigned short* srcA; int mode; int kbase;
        if (k0 < 1024) { srcA = A1; mode = a1Mode; kbase = k0; }
        else           { srcA = A2; mode = a2Mode; kbase = k0 - 1024; }
        {
            int m = tid >> 2, ch = tid & 3;
            int kc = (ch ^ ((m >> 1) & 3)) * 8;
            int rr = maprow(row0 + m, mode);
            gload_lds16(srcA + (size_t)rr * 1024 + kbase + kc, &As[tid * 8]);
        }
        #pragma unroll
        for (int rnd = 0; rnd < 2; ++rnd) {
            int c = rnd * 256 + tid;
            int n = c >> 2, ch = c & 3;
            int kc = (ch ^ ((n >> 1) & 3)) * 8;
            gload_lds16(WT + (size_t)(col0 + n) * ldw + k0 + kc, &Bs[c * 8]);
        }
        __syncthreads();
        bf16x8 af[4], bf_[2];
        #pragma unroll
        for (int i = 0; i < 4; ++i)
            af[i] = *(const bf16x8*)(&As[(i * 16 + fr) * 32 + fko]);
        #pragma unroll
        for (int j = 0; j < 2; ++j)
            bf_[j] = *(const bf16x8*)(&Bs[(wc + j * 16 + fr) * 32 + fko]);
        #pragma unroll
        for (int i = 0; i < 4; ++i)
            #pragma unroll
            for (int j = 0; j < 2; ++j)
                acc[i][j] = __builtin_amdgcn_mfma_f32_16x16x32_bf16(
                    af[i], bf_[j], acc[i][j], 0, 0, 0);
        __syncthreads();
    }

    const int qrow = (lane >> 4) * 4;
    const int qcol = lane & 15;
    #pragma unroll
    for (int i = 0; i < 4; ++i) {
        int rbase = row0 + i * 16 + qrow;
        #pragma unroll
        for (int j = 0; j < 2; ++j) {
            int c = col0 + wc + j * 16 + qcol;
            float bv = bias ? bias[c] : 0.0f;
            #pragma unroll
            for (int reg = 0; reg < 4; ++reg) {
                int r = rbase + reg;
                float vv = acc[i][j][reg] + bv;
                if (act) vv = gelu_f(vv);
                if (resid) vv += resid[(size_t)r * 1024 + c];
                if (Cf) Cf[(size_t)r * 1024 + c] = vv;
                if (Cb) Cb[(size_t)r * 1024 + c] = f2b(vv);
            }
        }
    }
}

// fp32 -> bf16 elementwise cast
__global__ __launch_bounds__(256) void cast_f2b(
    const float* __restrict__ in, unsigned short* __restrict__ out, int n)
{
    int i = (blockIdx.x * 256 + threadIdx.x) * 4;
    if (i >= n) return;
    float4 v = *(const float4*)(in + i);
    ushort4 o;
    o.x = f2b(v.x); o.y = f2b(v.y); o.z = f2b(v.z); o.w = f2b(v.w);
    *(ushort4*)(out + i) = o;
}

// All weight transposes+casts in one dispatch. grid (32, 64, 9).
__global__ __launch_bounds__(256) void tcast_all(
    const float* __restrict__ Wq, const float* __restrict__ Wk,
    const float* __restrict__ Wv, const float* __restrict__ We1,
    const float* __restrict__ Wu1, const float* __restrict__ Wu2,
    const float* __restrict__ Wi1,
    unsigned short* __restrict__ WT_all, unsigned short* __restrict__ Wu1T,
    unsigned short* __restrict__ Wu2T, unsigned short* __restrict__ Wi1T)
{
    const int z = blockIdx.z;
    const float* src; unsigned short* dst; int R;
    switch (z) {
        case 0: src = Wq;            dst = WT_all;               R = 1024; break;
        case 1: src = Wk;            dst = WT_all + 1024 * 1024; R = 1024; break;
        case 2: src = Wv;            dst = WT_all + 2048 * 1024; R = 1024; break;
        case 3: src = We1;           dst = WT_all + 3072 * 1024; R = 1024; break;
        case 4: src = We1 + 1048576; dst = WT_all + 4096 * 1024; R = 1024; break;
        case 5: src = We1 + 2097152; dst = WT_all + 5120 * 1024; R = 1024; break;
        case 6: src = Wu1;           dst = Wu1T;                 R = 2048; break;
        case 7: src = Wu2;           dst = Wu2T;                 R = 1024; break;
        default: src = Wi1;          dst = Wi1T;                 R = 2048; break;
    }
    const int rt = blockIdx.y * 32;
    if (rt >= R) return;
    const int ct = blockIdx.x * 32;
    __shared__ float t[32][33];
    const int tx = threadIdx.x & 31, ty = threadIdx.x >> 5;
    #pragma unroll
    for (int s = 0; s < 4; ++s)
        t[ty + s * 8][tx] = src[(size_t)(rt + ty + s * 8) * 1024 + ct + tx];
    __syncthreads();
    #pragma unroll
    for (int s = 0; s < 4; ++s)
        dst[(size_t)(ct + ty + s * 8) * R + rt + tx] = f2b(t[tx][ty + s * 8]);
}

// bias_all[5120] = [bq | bk | bv | 0 | 0]; zeroes accum scratch and il
__global__ void build_bias(const float* __restrict__ bq,
                           const float* __restrict__ bk,
                           const float* __restrict__ bv,
                           float* __restrict__ bias_all,
                           float* __restrict__ acc,
                           float* __restrict__ il)
{
    int i = blockIdx.x * 256 + threadIdx.x;
    if (i < 4) acc[i] = 0.f;
    if (i < 7168) il[i] = 0.f;
    if (i >= 5120) return;
    int seg = i >> 10, c = i & 1023;
    float v = 0.f;
    if (seg == 0) v = bq[c];
    else if (seg == 1) v = bk[c];
    else if (seg == 2) v = bv[c];
    bias_all[i] = v;
}

// ---------------------------------------------------------------------------
// One block per (b,n): edge MLP + logits + softmax + messages (bf16 in/out).
// All 7 m-partials in registers -> one reduction phase (2 barriers).
// msg may alias la (each block reads only its own la row, into regs first).
// ---------------------------------------------------------------------------
__global__ __launch_bounds__(256) void attn_msg_b(
    const unsigned short* __restrict__ q, const unsigned short* __restrict__ k,
    const unsigned short* __restrict__ v,
    const unsigned short* __restrict__ la, const unsigned short* __restrict__ rb,
    const float* __restrict__ cc,
    const float* __restrict__ We2, const float* __restrict__ be2,
    float* __restrict__ attn_out, unsigned short* __restrict__ msg)
{
    const int bn = blockIdx.x;
    const int b = bn / 7, n = bn % 7;
    const int tid = threadIdx.x;
    const int lane = tid & 63, wv = tid >> 6;
    const int d0 = tid * 4;
    __shared__ float red[4][14];
    __shared__ float sm[7];

    float qv[4], lav[4], wev[4];
    {
        ushort4 q4 = *(const ushort4*)(q + (size_t)bn * 1024 + d0);
        ushort4 l4 = *(const ushort4*)(la + (size_t)bn * 1024 + d0);
        float4 c4 = *(const float4*)(cc + (size_t)b * 1024 + d0);
        float4 w4 = *(const float4*)(We2 + d0);
        qv[0] = b2f(q4.x); qv[1] = b2f(q4.y); qv[2] = b2f(q4.z); qv[3] = b2f(q4.w);
        lav[0] = b2f(l4.x) + c4.x; lav[1] = b2f(l4.y) + c4.y;
        lav[2] = b2f(l4.z) + c4.z; lav[3] = b2f(l4.w) + c4.w;
        wev[0] = w4.x; wev[1] = w4.y; wev[2] = w4.z; wev[3] = w4.w;
    }

    float s1a[7], s2a[7];
    #pragma unroll
    for (int m = 0; m < 7; ++m) {
        ushort4 k4 = *(const ushort4*)(k  + (size_t)(b * 7 + m) * 1024 + d0);
        ushort4 r4 = *(const ushort4*)(rb + (size_t)(b * 7 + m) * 1024 + d0);
        s1a[m] = qv[0] * b2f(k4.x) + qv[1] * b2f(k4.y)
               + qv[2] * b2f(k4.z) + qv[3] * b2f(k4.w);
        s2a[m] = gelu_f(lav[0] + b2f(r4.x)) * wev[0]
               + gelu_f(lav[1] + b2f(r4.y)) * wev[1]
               + gelu_f(lav[2] + b2f(r4.z)) * wev[2]
               + gelu_f(lav[3] + b2f(r4.w)) * wev[3];
    }
    #pragma unroll
    for (int m = 0; m < 7; ++m) {
        float x1 = s1a[m], x2 = s2a[m];
        #pragma unroll
        for (int off = 32; off > 0; off >>= 1) {
            x1 += __shfl_down(x1, off);
            x2 += __shfl_down(x2, off);
        }
        if (lane == 0) { red[wv][m] = x1; red[wv][7 + m] = x2; }
    }
    __syncthreads();
    if (tid == 0) {
        float l[7];
        #pragma unroll
        for (int m = 0; m < 7; ++m) {
            float d1 = red[0][m] + red[1][m] + red[2][m] + red[3][m];
            float d2 = red[0][7 + m] + red[1][7 + m] + red[2][7 + m] + red[3][7 + m];
            l[m] = d1 * (1.0f / 32.0f) + d2 + be2[0]
                 + (c_adj[n * 7 + m] - 1.0f) * 10000.0f;
        }
        float mx = l[0];
        #pragma unroll
        for (int m = 1; m < 7; ++m) mx = fmaxf(mx, l[m]);
        float e[7], s = 0.f;
        #pragma unroll
        for (int m = 0; m < 7; ++m) { e[m] = __expf(l[m] - mx); s += e[m]; }
        float inv = 1.0f / s;
        #pragma unroll
        for (int m = 0; m < 7; ++m) {
            float wgt = e[m] * inv;
            sm[m] = wgt;
            attn_out[(size_t)bn * 7 + m] = wgt;
        }
    }
    __syncthreads();
    float wr_[7];
    #pragma unroll
    for (int m = 0; m < 7; ++m) wr_[m] = sm[m];
    float s0 = 0.f, s1 = 0.f, s2 = 0.f, s3 = 0.f;
    #pragma unroll
    for (int m = 0; m < 7; ++m) {
        ushort4 v4 = *(const ushort4*)(v + (size_t)(b * 7 + m) * 1024 + d0);
        s0 += wr_[m] * b2f(v4.x); s1 += wr_[m] * b2f(v4.y);
        s2 += wr_[m] * b2f(v4.z); s3 += wr_[m] * b2f(v4.w);
    }
    ushort4 o;
    o.x = f2b(s0); o.y = f2b(s1); o.z = f2b(s2); o.w = f2b(s3);
    *(ushort4*)(msg + (size_t)bn * 1024 + d0) = o;
}

// ---------------------------------------------------------------------------
// Fused tail: per-b softmax/cap/imp + fused = sum_n imp*upd + physics
// partials. upd read ONCE; fused stays in LDS. (logits have no bi2 --
// softmax is shift-invariant, so bi2 is dropped.)
// ---------------------------------------------------------------------------
__global__ __launch_bounds__(256) void imp_phys_k(
    const float* __restrict__ logits, const float* __restrict__ upd,
    float* __restrict__ imp_out, float* __restrict__ fused_out,
    float* __restrict__ accums)
{
    const int b = blockIdx.x;
    const int tid = threadIdx.x;
    const int lane = tid & 63, wv = tid >> 6;
    __shared__ float u[7][1024];
    __shared__ float f[1024];
    __shared__ float wsh[7];
    __shared__ float wred[4][36];

    for (int idx = tid; idx < 7 * 1024; idx += 256)
        u[idx >> 10][idx & 1023] = upd[(size_t)b * 7168 + idx];

    if (tid == 0) {
        float l[7], e[7];
        float mx = -1e30f;
        for (int i = 0; i < 7; ++i) { l[i] = logits[b * 7 + i]; mx = fmaxf(mx, l[i]); }
        float s = 0.f;
        for (int i = 0; i < 7; ++i) { e[i] = expf(l[i] - mx); s += e[i]; }
        float inv = 1.0f / s;
        float imp[7];
        for (int i = 0; i < 7; ++i) imp[i] = e[i] * inv;
        const float cap[7] = {1.f, 1.f, 1.f, 0.26f, 1.f, 1.f, 0.24f};
        const float fr[7]  = {1.f, 1.f, 1.f, 0.f,   1.f, 1.f, 0.f};
        float capped[7], capsum = 0.f, fmass = 0.f;
        for (int i = 0; i < 7; ++i) {
            capped[i] = fminf(imp[i], cap[i]);
            capsum += capped[i];
            fmass += imp[i] * fr[i];
        }
        float residual = fmaxf(1.0f - capsum, 0.0f);
        float redis[7], rs = 0.f;
        for (int i = 0; i < 7; ++i) {
            float fs = (fmass > 1e-6f) ? imp[i] * fr[i] / fmaxf(fmass, 1e-6f)
                                       : fr[i] * 0.2f;
            redis[i] = capped[i] + fs * residual;
            rs += redis[i];
        }
        float invr = 1.0f / fmaxf(rs, 1e-6f);
        for (int i = 0; i < 7; ++i) {
            float wi = redis[i] * invr;
            wsh[i] = wi;
            imp_out[b * 7 + i] = wi;
        }
    }
    __syncthreads();

    float wr[7];
    #pragma unroll
    for (int i = 0; i < 7; ++i) wr[i] = wsh[i];
    #pragma unroll
    for (int j = 0; j < 4; ++j) {
        int d = tid + j * 256;
        float s = 0.f;
        #pragma unroll
        for (int nn2 = 0; nn2 < 7; ++nn2)
            s += wr[nn2] * u[nn2][d];
        f[d] = s;
        fused_out[(size_t)b * 1024 + d] = s;
    }
    __syncthreads();

    float vals[36];
    #pragma unroll
    for (int i = 0; i < 36; ++i) vals[i] = 0.f;
    for (int d = tid; d < 1024; d += 256) {
        float x[7];
        #pragma unroll
        for (int n = 0; n < 7; ++n) x[n] = u[n][d];
        float fv = f[d];
        int idx = 0;
        #pragma unroll
        for (int n = 0; n < 7; ++n) {
            #pragma unroll
            for (int m = n; m < 7; ++m) vals[idx++] += x[n] * x[m];
        }
        #pragma unroll
        for (int n = 0; n < 7; ++n) vals[28 + n] += x[n] * fv;
        vals[35] += fv * fv;
    }
    #pragma unroll
    for (int i = 0; i < 36; ++i) {
        float s = vals[i];
        #pragma unroll
        for (int off = 32; off > 0; off >>= 1) s += __shfl_down(s, off);
        if (lane == 0) wred[wv][i] = s;
    }
    __syncthreads();
    if (tid == 0) {
        float tv[36];
        for (int i = 0; i < 36; ++i)
            tv[i] = wred[0][i] + wred[1][i] + wred[2][i] + wred[3][i];
        auto didx = [](int n, int m) -> int {
            if (n > m) { int t = n; n = m; m = t; }
            return n * 7 - n * (n - 1) / 2 + (m - n);
        };
        float norms[7];
        for (int n = 0; n < 7; ++n) norms[n] = sqrtf(tv[didx(n, n)]);
        float e = 0.f, nl = 0.f;
        for (int n = 0; n < 7; ++n)
            for (int m = 0; m < 7; ++m) {
                float cos_ = tv[didx(n, m)] / fmaxf(norms[n] * norms[m], 1e-8f);
                float adj = c_adj[n * 7 + m];
                e += (1.0f - cos_) * adj;
                if (adj == 0.0f && n != m) nl += fmaxf(cos_ - 0.35f, 0.0f);
            }
        float fnorm = sqrtf(tv[35]);
        float al = 0.f;
        for (int n = 0; n < 7; ++n) {
            float cosn = tv[28 + n] /
                         (fmaxf(norms[n], 1e-12f) * fmaxf(fnorm, 1e-12f));
            al += 1.0f - cosn;
        }
        atomicAdd(&accums[0], e);
        atomicAdd(&accums[1], nl);
        atomicAdd(&accums[2], al);
    }
}

__global__ void finalize_k(const float* __restrict__ a,
                           float* __restrict__ phys_o,
                           float* __restrict__ align_o)
{
    phys_o[0]  = a[0] / 41.0f + 0.5f * (a[1] / 8.0f);
    align_o[0] = a[2] * (1.0f / 7168.0f);
}

extern "C" void kernel_launch(void* const* d_in, const int* in_sizes, int n_in,
                              void* d_out, int out_size, void* d_ws, size_t ws_size,
                              hipStream_t stream)
{
    const float* nodes = (const float*)d_in[0];
    const float* Wq  = (const float*)d_in[1];
    const float* bq  = (const float*)d_in[2];
    const float* Wk  = (const float*)d_in[3];
    const float* bk  = (const float*)d_in[4];
    const float* Wv  = (const float*)d_in[5];
    const float* bv  = (const float*)d_in[6];
    const float* We1 = (const float*)d_in[7];
    const float* be1 = (const float*)d_in[8];
    const float* We2 = (const float*)d_in[9];
    const float* be2 = (const float*)d_in[10];
    const float* Wu1 = (const float*)d_in[11];
    const float* bu1 = (const float*)d_in[12];
    const float* Wu2 = (const float*)d_in[13];
    const float* bu2 = (const float*)d_in[14];
    const float* Wi1 = (const float*)d_in[15];
    const float* bi1 = (const float*)d_in[16];
    const float* Wi2 = (const float*)d_in[17];
    const float* bi2 = (const float*)d_in[18];
    (void)bi2;   // constant shift of all imp logits: softmax-invariant

    float* out = (float*)d_out;
    float* fused_o = out;                            // 1,048,576
    float* upd_o   = out + 1048576;                  // 7,340,032
    float* imp_o   = out + 1048576 + 7340032;        // 7,168
    float* attn_o  = imp_o + 7168;                   // 50,176
    float* phys_o  = attn_o + 50176;                 // 1
    float* align_o = phys_o + 1;                     // 1

    const size_t BIG = 7340032;   // B*N*D
    const size_t MEG = 1048576;   // D*D
    char* p = (char*)d_ws;
    unsigned short* nodes_b = (unsigned short*)p; p += BIG * 2;
    unsigned short* qb      = (unsigned short*)p; p += BIG * 2;   // seg 0; reused: h_u
    unsigned short* kb      = (unsigned short*)p; p += BIG * 2;   // seg 1; reused: upd_b
    unsigned short* vb      = (unsigned short*)p; p += BIG * 2;   // seg 2
    unsigned short* lab     = (unsigned short*)p; p += BIG * 2;   // seg 3; reused: msg
    unsigned short* rbb     = (unsigned short*)p; p += BIG * 2;   // seg 4
    unsigned short* WT_all  = (unsigned short*)p; p += (size_t)6144 * 1024 * 2;
    unsigned short* Wu1T    = (unsigned short*)p; p += 2 * MEG * 2;
    unsigned short* Wu2T    = (unsigned short*)p; p += MEG * 2;
    unsigned short* Wi1T    = (unsigned short*)p; p += 2 * MEG * 2;
    float* bias_all = (float*)p; p += 5120 * 4;
    float* ccf = (float*)p; p += MEG * 4;
    float* il  = (float*)p; p += 7168 * 4;
    float* acc = (float*)p; p += 4 * 4;
    unsigned short* msgb = lab;   // alias: safe (see attn_msg_b)
    unsigned short* hub  = qb;
    unsigned short* updb = kb;

    dim3 blk(256);
    dim3 blk512(512);

    // prep
    cast_f2b<<<dim3(7168), blk, 0, stream>>>(nodes, nodes_b, 7340032);
    tcast_all<<<dim3(32, 64, 9), blk, 0, stream>>>(Wq, Wk, Wv, We1, Wu1, Wu2, Wi1,
                                                   WT_all, Wu1T, Wu2T, Wi1T);
    build_bias<<<dim3(28), blk, 0, stream>>>(bq, bk, bv, bias_all, acc, il);

    // fused q|k|v|la|rb : N=5120, segmented bf16 out into qb..rbb
    gemm128db<<<dim3(40, 56), blk, 0, stream>>>(
        nodes_b, 0, nullptr, 0, WT_all, 1024, bias_all, nullptr,
        nullptr, qb, BIG, 1024, 0);

    // cc = nodes[:,-1] @ Wc + be1 (fp32 out), WcT at WT_all row 5120
    gemm64x128<<<dim3(8, 16), blk, 0, stream>>>(
        nodes_b, 1, nullptr, 0, WT_all + (size_t)5120 * 1024, 1024, be1, nullptr,
        ccf, nullptr, 1024, 0);

    // attention + messages (msg overwrites la)
    attn_msg_b<<<dim3(7168), blk, 0, stream>>>(qb, kb, vb, lab, rbb, ccf, We2, be2,
                                               attn_o, msgb);

    // h_u = gelu([nodes|msg] @ Wu1 + bu1)
    gemm128x8w<<<dim3(8, 56), blk512, 0, stream>>>(
        nodes_b, 0, msgb, 0, Wu1T, 2048, bu1, nullptr, nullptr, hub, 0, 2048, 1,
        nullptr, nullptr);
    // updated = h_u @ Wu2 + bu2 + nodes (fp32 out + bf16 copy)
    gemm128x8w<<<dim3(8, 56), blk512, 0, stream>>>(
        hub, 0, nullptr, 0, Wu2T, 1024, bu2, nodes, upd_o, updb, 0, 1024, 0,
        nullptr, nullptr);
    // imp logits: il[row] = sum_c gelu(([updated|ctx] @ Wi1 + bi1)[row,c]) * Wi2[c]
    // (h_i never materialized; bi2 dropped -- softmax-invariant)
    gemm128x8w<<<dim3(8, 56), blk512, 0, stream>>>(
        updb, 0, updb, 2, Wi1T, 2048, bi1, nullptr, nullptr, nullptr, 0, 2048, 1,
        Wi2, il);

    // tail
    imp_phys_k<<<dim3(1024), blk, 0, stream>>>(il, upd_o, imp_o, fused_o, acc);
    finalize_k<<<1, 1, 0, stream>>>(acc, phys_o, align_o);
}